// Round 10
// baseline (1069.566 us; speedup 1.0000x reference)
//
#include <hip/hip_runtime.h>
#include <math.h>

#define BB 16
#define NN 4096
#define SS 512
#define KK 32
#define NPIX (BB*SS*KK)          /* 262144 pixels (b,s,k) */
#define NGRP (BB*SS)             /* 8192 groups */

static constexpr float R2F  = (float)0.16000000000000003;  // RADIUS**2 as f32
static constexpr float EPSF = 1e-5f;

// ---------------- workspace layout (bytes) ----------------
constexpr size_t OFF_NXYZ = 0;                     // B*S*3 f32  = 98304
constexpr size_t OFF_GRP  = 98304;                 // B*S*NS i32 = 1048576
constexpr size_t OFF_P1   = 98304 + 1048576;       // 2*64*32 f64  = 32768
constexpr size_t OFF_P2   = OFF_P1 + 32768;
constexpr size_t OFF_P3   = OFF_P2 + 32768;        // 2*128*32 f64 = 65536
constexpr size_t OFF_MR1  = OFF_P3 + 65536;        // 64*2 f32
constexpr size_t OFF_MR2  = OFF_MR1 + 512;
constexpr size_t OFF_MR3  = OFF_MR2 + 512;         // 128*2 f32
constexpr size_t OFF_Z3   = 2*1024*1024;
constexpr size_t Z3SZ     = (size_t)NPIX*128*4;    // 134217728
constexpr size_t OFF_Z2   = OFF_Z3 + Z3SZ;         // 136MB
constexpr size_t Z2SZ     = (size_t)NPIX*64*4;     // 67108864
constexpr size_t NEED_Z3  = OFF_Z3 + Z3SZ;         // ~136MB
constexpr size_t NEED_Z2  = OFF_Z2 + Z2SZ;         // ~203MB

// DPP wave64 reduction steps: row_shr:1,2,4,8 then row_bcast:15, row_bcast:31.
// Invalid lanes return `old` (= current value) -> no-op combine. Result lane 63.
#define DPP_FMAX(v, ctrl) { int _t = __builtin_amdgcn_update_dpp(              \
      __float_as_int(v), __float_as_int(v), ctrl, 0xf, 0xf, false);            \
      v = fmaxf(v, __int_as_float(_t)); }
#define DPP_UMIN(v, ctrl) { unsigned _t = (unsigned)__builtin_amdgcn_update_dpp( \
      (int)(v), (int)(v), ctrl, 0xf, 0xf, false);                              \
      v = (v < _t ? v : _t); }

// ======================= FPS =======================
// Round-10: ILP batch-pairing. One block (512 thr) carries TWO independent
// batches IN-THREAD (not split across waves like r7's failed phase-lock):
// every thread owns 8 pts of batch A and 8 pts of batch B. The two
// select/update/reduce chains are independent -> compiler interleaves them,
// filling each batch's LDS-latency stalls with the other's VALU work, and
// ONE barrier per period serves a step of BOTH batches. Per-batch selection
// logic is bit-identical to the r6/r9 verified DPP reduction.
// LDS: 2x64KB pt4 + keys + hist ~ 135KB (<160KB; 128KB precedent m201).
// Also zeroes the stats partials (replaces the hipMemsetAsync dispatch).
__global__ __launch_bounds__(512) void fps_kernel(const float* __restrict__ xyz,
        float* __restrict__ out0, float* __restrict__ nxyz, double* __restrict__ pzero){
  const int t  = threadIdx.x;
  const int bA = blockIdx.x*2, bB = bA+1;
  const float* xA = xyz + (size_t)bA*3*NN;
  const float* xB = xyz + (size_t)bB*3*NN;
  __shared__ float4 ptA[NN];                       // 64 KB
  __shared__ float4 ptB[NN];                       // 64 KB
  __shared__ __align__(16) unsigned long long skA[2][8], skB[2][8];
  __shared__ int hA[SS], hB[SS];
  // zero stats partials p1+p2+p3 = 131072 B = 16384 f64 (8 blocks x 512 thr)
  for (int i = blockIdx.x*512 + t; i < 16384; i += 8*512) pzero[i] = 0.0;
  const int lane = t & 63, wv = t >> 6;            // wv in [0,8)
  float rxA[8],ryA[8],rzA[8],rdA[8], rxB[8],ryB[8],rzB[8],rdB[8];
#pragma unroll
  for (int j=0;j<8;j++){
    int i = t + 512*j;
    float x=xA[i], y=xA[NN+i], z=xA[2*NN+i];
    rxA[j]=x; ryA[j]=y; rzA[j]=z; ptA[i]=make_float4(x,y,z,0.0f); rdA[j]=1e10f;
    x=xB[i]; y=xB[NN+i]; z=xB[2*NN+i];
    rxB[j]=x; ryB[j]=y; rzB[j]=z; ptB[i]=make_float4(x,y,z,0.0f); rdB[j]=1e10f;
  }
  __syncthreads();
  int farA = 0, farB = 0;
  for (int s=0;s<SS;s++){
    const int buf = s & 1;
    float4 cA = ptA[farA];                         // two independent LDS reads
    float4 cB = ptB[farB];
    if (t==0){ hA[s]=farA; hB[s]=farB; }
    float bvA = -1.0f, bvB = -1.0f;
#pragma unroll
    for (int j=0;j<8;j++){
      float dx=__fsub_rn(rxA[j],cA.x), dy=__fsub_rn(ryA[j],cA.y), dz=__fsub_rn(rzA[j],cA.z);
      float d2=__fadd_rn(__fadd_rn(__fmul_rn(dx,dx),__fmul_rn(dy,dy)),__fmul_rn(dz,dz));
      float nd=fminf(rdA[j],d2); rdA[j]=nd; bvA=fmaxf(bvA,nd);
      dx=__fsub_rn(rxB[j],cB.x); dy=__fsub_rn(ryB[j],cB.y); dz=__fsub_rn(rzB[j],cB.z);
      d2=__fadd_rn(__fadd_rn(__fmul_rn(dx,dx),__fmul_rn(dy,dy)),__fmul_rn(dz,dz));
      nd=fminf(rdB[j],d2); rdB[j]=nd; bvB=fmaxf(bvB,nd);
    }
    // wave max (lane 63) + readlane broadcast, both batches (indep chains)
    DPP_FMAX(bvA,0x111); DPP_FMAX(bvB,0x111);
    DPP_FMAX(bvA,0x112); DPP_FMAX(bvB,0x112);
    DPP_FMAX(bvA,0x114); DPP_FMAX(bvB,0x114);
    DPP_FMAX(bvA,0x118); DPP_FMAX(bvB,0x118);
    DPP_FMAX(bvA,0x142); DPP_FMAX(bvB,0x142);
    DPP_FMAX(bvA,0x143); DPP_FMAX(bvB,0x143);
    const float vmA = __int_as_float(__builtin_amdgcn_readlane(__float_as_int(bvA), 63));
    const float vmB = __int_as_float(__builtin_amdgcn_readlane(__float_as_int(bvB), 63));
    // lane-local lowest matching index (descending j: last write = lowest idx)
    unsigned cnA = 0xFFFFFFFFu, cnB = 0xFFFFFFFFu;
#pragma unroll
    for (int j=7;j>=0;j--){
      if (rdA[j]==vmA) cnA = (unsigned)(t+512*j);
      if (rdB[j]==vmB) cnB = (unsigned)(t+512*j);
    }
    // wave min of candidate index (lane 63)
    DPP_UMIN(cnA,0x111); DPP_UMIN(cnB,0x111);
    DPP_UMIN(cnA,0x112); DPP_UMIN(cnB,0x112);
    DPP_UMIN(cnA,0x114); DPP_UMIN(cnB,0x114);
    DPP_UMIN(cnA,0x118); DPP_UMIN(cnB,0x118);
    DPP_UMIN(cnA,0x142); DPP_UMIN(cnB,0x142);
    DPP_UMIN(cnA,0x143); DPP_UMIN(cnB,0x143);
    if (lane==63){
      skA[buf][wv] = ((unsigned long long)(unsigned)__float_as_int(vmA) << 32)
                   | (unsigned)(~cnA);
      skB[buf][wv] = ((unsigned long long)(unsigned)__float_as_int(vmB) << 32)
                   | (unsigned)(~cnB);
    }
    __syncthreads();   // one barrier serves a step of BOTH batches
    {
      unsigned long long k0=skA[buf][0],k1=skA[buf][1],k2=skA[buf][2],k3=skA[buf][3];
      unsigned long long k4=skA[buf][4],k5=skA[buf][5],k6=skA[buf][6],k7=skA[buf][7];
      unsigned long long p0=skB[buf][0],p1=skB[buf][1],p2=skB[buf][2],p3=skB[buf][3];
      unsigned long long p4=skB[buf][4],p5=skB[buf][5],p6=skB[buf][6],p7=skB[buf][7];
      unsigned long long a01=(k0>k1)?k0:k1, a23=(k2>k3)?k2:k3;
      unsigned long long a45=(k4>k5)?k4:k5, a67=(k6>k7)?k6:k7;
      unsigned long long b01=(p0>p1)?p0:p1, b23=(p2>p3)?p2:p3;
      unsigned long long b45=(p4>p5)?p4:p5, b67=(p6>p7)?p6:p7;
      unsigned long long aA=(a01>a23)?a01:a23, aB=(a45>a67)?a45:a67;
      unsigned long long bA2=(b01>b23)?b01:b23, bB2=(b45>b67)?b45:b67;
      unsigned long long mA=(aA>aB)?aA:aB, mB=(bA2>bB2)?bA2:bB2;
      farA = (int)(~(unsigned)(mA & 0xFFFFFFFFull));
      farB = (int)(~(unsigned)(mB & 0xFFFFFFFFull));
    }
    // no WAR barrier: sk*[buf] rewritten at step s+2, after step s+1's barrier
  }
  __syncthreads();
  // cooperative writeout (once); SS == 512 == blockDim
  {
    int idx = hA[t];
    float4 c = ptA[idx];
    int gid = bA*SS + t;
    nxyz[gid*3+0]=c.x; nxyz[gid*3+1]=c.y; nxyz[gid*3+2]=c.z;
    out0[(bA*3+0)*SS+t]=c.x; out0[(bA*3+1)*SS+t]=c.y; out0[(bA*3+2)*SS+t]=c.z;
    idx = hB[t];
    c = ptB[idx];
    gid = bB*SS + t;
    nxyz[gid*3+0]=c.x; nxyz[gid*3+1]=c.y; nxyz[gid*3+2]=c.z;
    out0[(bB*3+0)*SS+t]=c.x; out0[(bB*3+1)*SS+t]=c.y; out0[(bB*3+2)*SS+t]=c.z;
  }
}

// ======================= ball query (unchanged, passing) =======================
__global__ __launch_bounds__(256) void ball_kernel(const float* __restrict__ xyz,
        const float* __restrict__ nxyz, int* __restrict__ grp){
  const int gw   = (blockIdx.x*256 + threadIdx.x) >> 6;
  const int lane = threadIdx.x & 63;
  if (gw >= NGRP) return;
  const int b = gw / SS;
  const float* xb = xyz + (size_t)b*3*NN;
  const float nx=nxyz[gw*3+0], ny=nxyz[gw*3+1], nz=nxyz[gw*3+2];
  const float sn = __fadd_rn(__fadd_rn(__fmul_rn(nx,nx),__fmul_rn(ny,ny)),__fmul_rn(nz,nz));
  int cnt=0, first=-1;
  int* g = grp + (size_t)gw*KK;
  for (int c=0;c<NN/64 && cnt<KK;c++){
    int i=c*64+lane;
    float x=xb[i], y=xb[NN+i], z=xb[2*NN+i];
    float sxx=__fadd_rn(__fadd_rn(__fmul_rn(x,x),__fmul_rn(y,y)),__fmul_rn(z,z));
    float dot=__fadd_rn(__fadd_rn(__fmul_rn(nx,x),__fmul_rn(ny,y)),__fmul_rn(nz,z));
    float sqr=__fsub_rn(__fadd_rn(sn,sxx),__fmul_rn(2.0f,dot));
    bool m = (sqr <= R2F);
    unsigned long long mask = __ballot(m);
    if (m){
      int pos = cnt + __popcll(mask & ((1ull<<lane)-1ull));
      if (pos < KK) g[pos] = i;
    }
    if (first<0 && mask) first = c*64 + (__ffsll((long long)mask) - 1);
    cnt += __popcll(mask);
  }
  if (cnt < KK && lane >= cnt && lane < KK) g[lane] = first;
}

// ======================= finalize (unchanged) =======================
__global__ void finalize_kernel(const double* __restrict__ part, float* __restrict__ mr, int C){
  int o = threadIdx.x;
  if (o < C){
    double s1=0.0, s2=0.0;
    for (int k=0;k<32;k++){ s1 += part[o*32+k]; s2 += part[(C+o)*32+k]; }
    const double n = (double)NPIX;
    double mean = s1/n;
    double var  = s2/n - mean*mean;
    mr[2*o]   = (float)mean;
    mr[2*o+1] = (float)(1.0/sqrt(var + (double)EPSF));
  }
}

// ======================= tiled MLP chain (unchanged from r9, passing) =======================
constexpr int XIN = 0;          // 6*68   = 408
constexpr int W0F = 408;        // 6*64   = 384
constexpr int B0F = 792;        // 64
constexpr int W1F = 856;        // 64*64  = 4096
constexpr int B1F = 4952;       // 64
constexpr int XBF = 5016;       // 64*68  = 4352
constexpr int SRF = 9368;       // 256  (f32 stats red, or u32 maxpool)
constexpr int W2F = 9624;       // 64*128 = 8192
constexpr int B2F = 17816;      // 128
constexpr int SM_SMALL = 9624;  // stages 1,2 (38.5 KB)
constexpr int SM_BIG   = 17944; // stages 3,4 (71.8 KB -> 2 blocks/CU)

template<int STAGE, bool STZ3, bool Z2IO>
__global__ __launch_bounds__(256,2) void mlp_kernel(
    const float* __restrict__ xyz, const float* __restrict__ pts,
    const float* __restrict__ nxyz, const int* __restrict__ grp,
    const float* __restrict__ w0, const float* __restrict__ b0,
    const float* __restrict__ mr1, const float* __restrict__ g0, const float* __restrict__ be0,
    const float* __restrict__ w1, const float* __restrict__ b1,
    const float* __restrict__ mr2, const float* __restrict__ g1, const float* __restrict__ be1,
    const float* __restrict__ w2, const float* __restrict__ b2,
    const float* __restrict__ mr3, const float* __restrict__ g2, const float* __restrict__ be2,
    double* __restrict__ part, float* __restrict__ out1,
    float* __restrict__ z2w, float* __restrict__ z3w)
{
  __shared__ float sm[(STAGE>=3)? SM_BIG : SM_SMALL];
  const int t   = threadIdx.x;
  const int blk = blockIdx.x;
  const int tx  = t & 15, ty = t >> 4;
  const int p0  = blk*64;
  const int slot = blk & 31;
  constexpr bool SKIP12 = (STAGE==3 && Z2IO);   // z2 sourced from global

  sm[SRF + t] = 0.0f;   // stats / maxpool slot (0.0f bits == 0u)

  if constexpr (!SKIP12){
    for (int i=t;i<384;i+=256){ int o=i/6, c=i-o*6; sm[W0F + c*64 + o] = w0[i]; }
    if (t<64) sm[B0F+t] = b0[t];
    if constexpr (STAGE>=2){
      for (int i=t;i<4096;i+=256){ int o=i&63, c=i>>6; sm[W1F + c*64 + o] = w1[o*64+c]; }
      if (t<64) sm[B1F+t] = b1[t];
    }
    for (int i=t;i<384;i+=256){
      int c=i>>6, px=i&63, p=p0+px, gid=p>>5, bb=p>>14;
      int idx = grp[p];
      float v;
      if (c<3) v = __fsub_rn(xyz[(size_t)bb*3*NN + c*NN + idx], nxyz[gid*3+c]);
      else     v = pts[(size_t)bb*3*NN + (c-3)*NN + idx];
      sm[XIN + c*68 + px] = v;
    }
  }
  if constexpr (STAGE>=3){
    for (int i=t;i<8192;i+=256){ int o=i&127, c=i>>7; sm[W2F + c*128 + o] = w2[o*64+c]; }
    if (t<128) sm[B2F+t] = b2[t];
  }
  __syncthreads();

  float z[4][4];
  if constexpr (SKIP12){
    // z2 (pre-norm) from global: same per-thread layout as the compute path
#pragma unroll
    for (int i=0;i<4;i++){
      float4 v = *(const float4*)&z2w[(size_t)(p0 + ty*4 + i)*64 + tx*4];
      z[i][0]=v.x; z[i][1]=v.y; z[i][2]=v.z; z[i][3]=v.w;
    }
  } else {
    // ---- layer 1: 6 -> 64 ----
#pragma unroll
    for (int i=0;i<4;i++)
#pragma unroll
      for (int j=0;j<4;j++) z[i][j]=0.0f;
#pragma unroll
    for (int k=0;k<6;k++){
      float4 xv = *(const float4*)&sm[XIN + k*68 + ty*4];
      float4 wv = *(const float4*)&sm[W0F + k*64 + tx*4];
      const float xs[4]={xv.x,xv.y,xv.z,xv.w};
      const float wsv[4]={wv.x,wv.y,wv.z,wv.w};
#pragma unroll
      for (int i=0;i<4;i++)
#pragma unroll
        for (int j=0;j<4;j++) z[i][j] = fmaf(xs[i], wsv[j], z[i][j]);
    }
#pragma unroll
    for (int i=0;i<4;i++)
#pragma unroll
      for (int j=0;j<4;j++) z[i][j] = __fadd_rn(z[i][j], sm[B0F + tx*4 + j]);

    if constexpr (STAGE==1){
#pragma unroll
      for (int j=0;j<4;j++){
        float s1=0.0f, s2=0.0f;
#pragma unroll
        for (int i=0;i<4;i++){ s1 = __fadd_rn(s1, z[i][j]); s2 = fmaf(z[i][j], z[i][j], s2); }
        atomicAdd(&sm[SRF + (tx*4+j)*2    ], s1);
        atomicAdd(&sm[SRF + (tx*4+j)*2 + 1], s2);
      }
      __syncthreads();
      if (t<128){ int ch=t>>1, m=t&1;
        atomicAdd(part + (size_t)((m? 64+ch : ch)*32 + slot), (double)sm[SRF+t]);
      }
      return;
    }

    // norm+relu(mr1) -> xbuf
#pragma unroll
    for (int j=0;j<4;j++){
      int ch = tx*4+j;
      float m=mr1[2*ch], r=mr1[2*ch+1], gg=g0[ch], bt=be0[ch];
      float4 o;
      o.x = fmaxf(fmaf(__fmul_rn(__fsub_rn(z[0][j],m),r), gg, bt), 0.0f);
      o.y = fmaxf(fmaf(__fmul_rn(__fsub_rn(z[1][j],m),r), gg, bt), 0.0f);
      o.z = fmaxf(fmaf(__fmul_rn(__fsub_rn(z[2][j],m),r), gg, bt), 0.0f);
      o.w = fmaxf(fmaf(__fmul_rn(__fsub_rn(z[3][j],m),r), gg, bt), 0.0f);
      *(float4*)&sm[XBF + ch*68 + ty*4] = o;
    }
    __syncthreads();

    // ---- layer 2: 64 -> 64 ----
#pragma unroll
    for (int i=0;i<4;i++)
#pragma unroll
      for (int j=0;j<4;j++) z[i][j]=0.0f;
#pragma unroll 8
    for (int k=0;k<64;k++){
      float4 xv = *(const float4*)&sm[XBF + k*68 + ty*4];
      float4 wv = *(const float4*)&sm[W1F + k*64 + tx*4];
      const float xs[4]={xv.x,xv.y,xv.z,xv.w};
      const float wsv[4]={wv.x,wv.y,wv.z,wv.w};
#pragma unroll
      for (int i=0;i<4;i++)
#pragma unroll
        for (int j=0;j<4;j++) z[i][j] = fmaf(xs[i], wsv[j], z[i][j]);
    }
#pragma unroll
    for (int i=0;i<4;i++)
#pragma unroll
      for (int j=0;j<4;j++) z[i][j] = __fadd_rn(z[i][j], sm[B1F + tx*4 + j]);

    if constexpr (STAGE==2){
      if constexpr (Z2IO){
#pragma unroll
        for (int i=0;i<4;i++)
          *(float4*)&z2w[(size_t)(p0 + ty*4 + i)*64 + tx*4]
              = make_float4(z[i][0], z[i][1], z[i][2], z[i][3]);
      }
#pragma unroll
      for (int j=0;j<4;j++){
        float s1=0.0f, s2=0.0f;
#pragma unroll
        for (int i=0;i<4;i++){ s1 = __fadd_rn(s1, z[i][j]); s2 = fmaf(z[i][j], z[i][j], s2); }
        atomicAdd(&sm[SRF + (tx*4+j)*2    ], s1);
        atomicAdd(&sm[SRF + (tx*4+j)*2 + 1], s2);
      }
      __syncthreads();
      if (t<128){ int ch=t>>1, m=t&1;
        atomicAdd(part + (size_t)((m? 64+ch : ch)*32 + slot), (double)sm[SRF+t]);
      }
      return;
    }
  }

  if constexpr (STAGE>=3){
    __syncthreads();   // WAR guard on XBF (harmless in SKIP12 path)
#pragma unroll
    for (int j=0;j<4;j++){
      int ch = tx*4+j;
      float m=mr2[2*ch], r=mr2[2*ch+1], gg=g1[ch], bt=be1[ch];
      float4 o;
      o.x = fmaxf(fmaf(__fmul_rn(__fsub_rn(z[0][j],m),r), gg, bt), 0.0f);
      o.y = fmaxf(fmaf(__fmul_rn(__fsub_rn(z[1][j],m),r), gg, bt), 0.0f);
      o.z = fmaxf(fmaf(__fmul_rn(__fsub_rn(z[2][j],m),r), gg, bt), 0.0f);
      o.w = fmaxf(fmaf(__fmul_rn(__fsub_rn(z[3][j],m),r), gg, bt), 0.0f);
      *(float4*)&sm[XBF + ch*68 + ty*4] = o;
    }
    __syncthreads();

    // ---- layer 3: 64 -> 128 ----
    float a3[4][8];
#pragma unroll
    for (int i=0;i<4;i++)
#pragma unroll
      for (int j=0;j<8;j++) a3[i][j]=0.0f;
#pragma unroll 4
    for (int k=0;k<64;k++){
      float4 xv  = *(const float4*)&sm[XBF + k*68  + ty*4];
      float4 wv0 = *(const float4*)&sm[W2F + k*128 + tx*4];
      float4 wv1 = *(const float4*)&sm[W2F + k*128 + 64 + tx*4];
      const float xs[4]={xv.x,xv.y,xv.z,xv.w};
      const float wsv[8]={wv0.x,wv0.y,wv0.z,wv0.w, wv1.x,wv1.y,wv1.z,wv1.w};
#pragma unroll
      for (int i=0;i<4;i++)
#pragma unroll
        for (int j=0;j<8;j++) a3[i][j] = fmaf(xs[i], wsv[j], a3[i][j]);
    }
#pragma unroll
    for (int i=0;i<4;i++)
#pragma unroll
      for (int j=0;j<8;j++){
        int ch = (j<4)? (tx*4+j) : (64+tx*4+(j-4));
        a3[i][j] = __fadd_rn(a3[i][j], sm[B2F + ch]);
      }

    if constexpr (STAGE==3){
      if constexpr (STZ3){
#pragma unroll
        for (int i=0;i<4;i++){
          size_t p = (size_t)(p0 + ty*4 + i)*128;
          *(float4*)&z3w[p + tx*4]      = make_float4(a3[i][0],a3[i][1],a3[i][2],a3[i][3]);
          *(float4*)&z3w[p + 64 + tx*4] = make_float4(a3[i][4],a3[i][5],a3[i][6],a3[i][7]);
        }
      }
#pragma unroll
      for (int j=0;j<8;j++){
        int ch = (j<4)? (tx*4+j) : (64+tx*4+(j-4));
        float s1=0.0f, s2=0.0f;
#pragma unroll
        for (int i=0;i<4;i++){ s1 = __fadd_rn(s1, a3[i][j]); s2 = fmaf(a3[i][j], a3[i][j], s2); }
        atomicAdd(&sm[SRF + ch*2    ], s1);
        atomicAdd(&sm[SRF + ch*2 + 1], s2);
      }
      __syncthreads();
      { int ch=t>>1, m=t&1;
        atomicAdd(part + (size_t)((m? 128+ch : ch)*32 + slot), (double)sm[SRF+t]);
      }
      return;
    }

    if constexpr (STAGE==4){
      const int grp_l = ty>>3;
      unsigned* omax = (unsigned*)sm;
#pragma unroll
      for (int j=0;j<8;j++){
        int ch = (j<4)? (tx*4+j) : (64+tx*4+(j-4));
        float m=mr3[2*ch], r=mr3[2*ch+1], gg=g2[ch], bt=be2[ch];
        float vmax=0.0f;
#pragma unroll
        for (int i=0;i<4;i++){
          float v = fmaxf(fmaf(__fmul_rn(__fsub_rn(a3[i][j],m),r), gg, bt), 0.0f);
          vmax = fmaxf(vmax, v);
        }
        atomicMax(&omax[SRF + grp_l*128 + ch], __float_as_uint(vmax));
      }
      __syncthreads();
      { int g = t>>7, o = t&127;
        int gid = blk*2 + g, bb = gid>>9, s = gid&511;
        out1[((size_t)(bb*128+o))*512 + s] = __uint_as_float(omax[SRF + t]);
      }
    }
  }
}

// ======================= maxpool reader (unchanged, passing) =======================
__global__ __launch_bounds__(256) void maxpool_kernel(const float* __restrict__ z3,
        const float* __restrict__ mr3, const float* __restrict__ g2,
        const float* __restrict__ be2, float* __restrict__ out1){
  const int t = threadIdx.x;
  const int g = blockIdx.x*2 + (t>>7);     // group id (b*SS+s)
  const int o = t & 127;
  const int bb = g >> 9, s = g & 511;
  const float* zp = z3 + (size_t)g*KK*128 + o;
  float m=mr3[2*o], r=mr3[2*o+1], gg=g2[o], bt=be2[o];
  float mx = 0.0f;                         // relu outputs are >= 0
#pragma unroll 8
  for (int k=0;k<KK;k++){
    float v = fmaxf(fmaf(__fmul_rn(__fsub_rn(zp[(size_t)k*128],m),r), gg, bt), 0.0f);
    mx = fmaxf(mx, v);
  }
  out1[((size_t)(bb*128+o))*SS + s] = mx;
}

// ======================= launch =======================
extern "C" void kernel_launch(void* const* d_in, const int* in_sizes, int n_in,
                              void* d_out, int out_size, void* d_ws, size_t ws_size,
                              hipStream_t stream){
  const float* xyz = (const float*)d_in[0];
  const float* pts = (const float*)d_in[1];
  const float* w0  = (const float*)d_in[2];  const float* b0  = (const float*)d_in[3];
  const float* g0  = (const float*)d_in[4];  const float* be0 = (const float*)d_in[5];
  const float* w1  = (const float*)d_in[6];  const float* b1  = (const float*)d_in[7];
  const float* g1  = (const float*)d_in[8];  const float* be1 = (const float*)d_in[9];
  const float* w2  = (const float*)d_in[10]; const float* b2  = (const float*)d_in[11];
  const float* g2  = (const float*)d_in[12]; const float* be2 = (const float*)d_in[13];

  float* out  = (float*)d_out;
  float* out1 = out + BB*3*SS;
  char*  ws   = (char*)d_ws;

  float*  nxyz = (float*)(ws + OFF_NXYZ);
  int*    grp  = (int*)  (ws + OFF_GRP);
  double* p1   = (double*)(ws + OFF_P1);
  double* p2   = (double*)(ws + OFF_P2);
  double* p3   = (double*)(ws + OFF_P3);
  float*  mr1  = (float*)(ws + OFF_MR1);
  float*  mr2  = (float*)(ws + OFF_MR2);
  float*  mr3  = (float*)(ws + OFF_MR3);
  float*  z3w  = (float*)(ws + OFF_Z3);
  float*  z2w  = (float*)(ws + OFF_Z2);

  const bool stz3 = (ws_size >= NEED_Z3);
  const bool stz2 = (ws_size >= NEED_Z2);   // implies stz3

  // p1/p2/p3 zeroing folded into fps_kernel (replaces hipMemsetAsync)
  fps_kernel <<<BB/2, 512, 0, stream>>>(xyz, out, nxyz, p1);
  ball_kernel<<<NGRP*64/256, 256, 0, stream>>>(xyz, nxyz, grp);

#define MLP_ARGS xyz, pts, nxyz, grp, w0, b0, mr1, g0, be0, w1, b1, mr2, g1, be1, w2, b2, mr3, g2, be2
  mlp_kernel<1,false,false><<<NPIX/64, 256, 0, stream>>>(MLP_ARGS, p1, out1, z2w, z3w);
  finalize_kernel<<<1,128,0,stream>>>(p1, mr1, 64);
  if (stz2) mlp_kernel<2,false,true ><<<NPIX/64, 256, 0, stream>>>(MLP_ARGS, p2, out1, z2w, z3w);
  else      mlp_kernel<2,false,false><<<NPIX/64, 256, 0, stream>>>(MLP_ARGS, p2, out1, z2w, z3w);
  finalize_kernel<<<1,128,0,stream>>>(p2, mr2, 64);
  if (stz2)      mlp_kernel<3,true ,true ><<<NPIX/64, 256, 0, stream>>>(MLP_ARGS, p3, out1, z2w, z3w);
  else if (stz3) mlp_kernel<3,true ,false><<<NPIX/64, 256, 0, stream>>>(MLP_ARGS, p3, out1, z2w, z3w);
  else           mlp_kernel<3,false,false><<<NPIX/64, 256, 0, stream>>>(MLP_ARGS, p3, out1, z2w, z3w);
  finalize_kernel<<<1,128,0,stream>>>(p3, mr3, 128);
  if (stz3) maxpool_kernel<<<NGRP/2, 256, 0, stream>>>(z3w, mr3, g2, be2, out1);
  else      mlp_kernel<4,false,false><<<NPIX/64, 256, 0, stream>>>(MLP_ARGS, p3, out1, z2w, z3w);
#undef MLP_ARGS
}

// Round 12
// 800.446 us; speedup vs baseline: 1.3362x; 1.3362x over previous
//
#include <hip/hip_runtime.h>
#include <math.h>

#define BB 16
#define NN 4096
#define SS 512
#define KK 32
#define NPIX (BB*SS*KK)          /* 262144 pixels (b,s,k) */
#define NGRP (BB*SS)             /* 8192 groups */

static constexpr float R2F  = (float)0.16000000000000003;  // RADIUS**2 as f32
static constexpr float EPSF = 1e-5f;

// ---------------- workspace layout (bytes) ----------------
constexpr size_t OFF_NXYZ = 0;                     // B*S*3 f32  = 98304
constexpr size_t OFF_GRP  = 98304;                 // B*S*NS i32 = 1048576
constexpr size_t OFF_P1   = 98304 + 1048576;       // 2*64*32 f64  = 32768
constexpr size_t OFF_P2   = OFF_P1 + 32768;
constexpr size_t OFF_P3   = OFF_P2 + 32768;        // 2*128*32 f64 = 65536
constexpr size_t OFF_MR1  = OFF_P3 + 65536;        // 64*2 f32
constexpr size_t OFF_MR2  = OFF_MR1 + 512;
constexpr size_t OFF_MR3  = OFF_MR2 + 512;         // 128*2 f32
constexpr size_t OFF_Z3   = 2*1024*1024;
constexpr size_t Z3SZ     = (size_t)NPIX*128*4;    // 134217728
constexpr size_t OFF_Z2   = OFF_Z3 + Z3SZ;         // 136MB
constexpr size_t Z2SZ     = (size_t)NPIX*64*4;     // 67108864
constexpr size_t NEED_Z3  = OFF_Z3 + Z3SZ;         // ~136MB
constexpr size_t NEED_Z2  = OFF_Z2 + Z2SZ;         // ~203MB

// Packed-u64 DPP max step with LITERAL dpp ctrl (builtin requires constant).
// key = (dist_bits<<32)|~idx; u64 max == (max dist, lowest index).
// bound_ctrl=false -> invalid lanes return old value (self-combine no-op).
#define DPP_U64MAX(key, ctrl) {                                                  \
    unsigned _hi = (unsigned)((key) >> 32), _lo = (unsigned)(key);               \
    unsigned _h2 = (unsigned)__builtin_amdgcn_update_dpp((int)_hi,(int)_hi,(ctrl),0xf,0xf,false); \
    unsigned _l2 = (unsigned)__builtin_amdgcn_update_dpp((int)_lo,(int)_lo,(ctrl),0xf,0xf,false); \
    unsigned long long _o = ((unsigned long long)_h2 << 32) | _l2;               \
    (key) = (_o > (key)) ? _o : (key); }

// ======================= FPS =======================
// Round-12 (= r11 candidate, compile-fixed): r9 structure (16 blocks x 512
// thr x 8 pts — measured-best 330us config). Single packed-u64 DPP max
// reduce replaces the two-stage {fmax chain -> readlane -> equality scan ->
// umin chain} (~300-400 serial cyc -> ~72). DPP levels: row_shr:1,2,4,8
// then row_bcast:15,31. Result in lane 63. Also zeroes stats partials
// (replaces the hipMemsetAsync dispatch).
__global__ __launch_bounds__(512) void fps_kernel(const float* __restrict__ xyz,
        float* __restrict__ out0, float* __restrict__ nxyz, double* __restrict__ pzero){
  const int b = blockIdx.x;
  const float* xb = xyz + (size_t)b*3*NN;
  __shared__ float4 pt4[NN];                       // 64 KB
  __shared__ __align__(16) unsigned long long skey[2][8];
  __shared__ int hist[SS];
  const int t = threadIdx.x;
  const int lane = t & 63, wv = t >> 6;            // wv in [0,8)
  // zero stats partials p1+p2+p3 = 131072 B = 16384 f64 (16 blocks x 512 thr)
  for (int i = b*512 + t; i < 16384; i += 16*512) pzero[i] = 0.0;
  float rx[8], ry[8], rz[8], rd[8];
#pragma unroll
  for (int j=0;j<8;j++){
    int i = t + 512*j;
    float x = xb[i], y = xb[NN+i], z = xb[2*NN+i];
    rx[j]=x; ry[j]=y; rz[j]=z;
    pt4[i] = make_float4(x,y,z,0.0f);
    rd[j]=1e10f;
  }
  __syncthreads();
  int far = 0;
  for (int s=0;s<SS;s++){
    const int buf = s & 1;
    float4 c = pt4[far];
    if (t==0) hist[s] = far;
    float bv = -1.0f; int bi = 0;
#pragma unroll
    for (int j=0;j<8;j++){
      float dx=__fsub_rn(rx[j],c.x), dy=__fsub_rn(ry[j],c.y), dz=__fsub_rn(rz[j],c.z);
      float d2=__fadd_rn(__fadd_rn(__fmul_rn(dx,dx),__fmul_rn(dy,dy)),__fmul_rn(dz,dz));
      float nd=fminf(rd[j],d2);
      rd[j]=nd;
      if (nd>bv){bv=nd;bi=t+512*j;}   // indices ascend with j -> first-max kept
    }
    // packed key: dist (>=0, bits monotone) hi, ~idx lo (u64 max -> lowest idx)
    unsigned long long key = ((unsigned long long)(unsigned)__float_as_int(bv) << 32)
                           | (unsigned)(~(unsigned)bi);
    DPP_U64MAX(key,0x111); DPP_U64MAX(key,0x112); DPP_U64MAX(key,0x114);
    DPP_U64MAX(key,0x118); DPP_U64MAX(key,0x142); DPP_U64MAX(key,0x143);
    if (lane==63) skey[buf][wv] = key;
    __syncthreads();   // only lgkm traffic outstanding -> cheap drain
    unsigned long long k0=skey[buf][0], k1=skey[buf][1], k2=skey[buf][2], k3=skey[buf][3];
    unsigned long long k4=skey[buf][4], k5=skey[buf][5], k6=skey[buf][6], k7=skey[buf][7];
    unsigned long long m01=(k0>k1)?k0:k1, m23=(k2>k3)?k2:k3;
    unsigned long long m45=(k4>k5)?k4:k5, m67=(k6>k7)?k6:k7;
    unsigned long long mA=(m01>m23)?m01:m23, mB=(m45>m67)?m45:m67;
    unsigned long long m =(mA>mB)?mA:mB;
    far = (int)(~(unsigned)(m & 0xFFFFFFFFull));
    // no WAR barrier: skey[buf] rewritten at step s+2, after step s+1's barrier
  }
  __syncthreads();
  // cooperative writeout (once); SS == 512 == blockDim
  {
    int idx = hist[t];
    float4 c = pt4[idx];
    int gid = b*SS + t;
    nxyz[gid*3+0]=c.x; nxyz[gid*3+1]=c.y; nxyz[gid*3+2]=c.z;
    out0[(b*3+0)*SS+t]=c.x; out0[(b*3+1)*SS+t]=c.y; out0[(b*3+2)*SS+t]=c.z;
  }
}

// ======================= ball query (unchanged, passing) =======================
__global__ __launch_bounds__(256) void ball_kernel(const float* __restrict__ xyz,
        const float* __restrict__ nxyz, int* __restrict__ grp){
  const int gw   = (blockIdx.x*256 + threadIdx.x) >> 6;
  const int lane = threadIdx.x & 63;
  if (gw >= NGRP) return;
  const int b = gw / SS;
  const float* xb = xyz + (size_t)b*3*NN;
  const float nx=nxyz[gw*3+0], ny=nxyz[gw*3+1], nz=nxyz[gw*3+2];
  const float sn = __fadd_rn(__fadd_rn(__fmul_rn(nx,nx),__fmul_rn(ny,ny)),__fmul_rn(nz,nz));
  int cnt=0, first=-1;
  int* g = grp + (size_t)gw*KK;
  for (int c=0;c<NN/64 && cnt<KK;c++){
    int i=c*64+lane;
    float x=xb[i], y=xb[NN+i], z=xb[2*NN+i];
    float sxx=__fadd_rn(__fadd_rn(__fmul_rn(x,x),__fmul_rn(y,y)),__fmul_rn(z,z));
    float dot=__fadd_rn(__fadd_rn(__fmul_rn(nx,x),__fmul_rn(ny,y)),__fmul_rn(nz,z));
    float sqr=__fsub_rn(__fadd_rn(sn,sxx),__fmul_rn(2.0f,dot));
    bool m = (sqr <= R2F);
    unsigned long long mask = __ballot(m);
    if (m){
      int pos = cnt + __popcll(mask & ((1ull<<lane)-1ull));
      if (pos < KK) g[pos] = i;
    }
    if (first<0 && mask) first = c*64 + (__ffsll((long long)mask) - 1);
    cnt += __popcll(mask);
  }
  if (cnt < KK && lane >= cnt && lane < KK) g[lane] = first;
}

// ======================= finalize (unchanged) =======================
__global__ void finalize_kernel(const double* __restrict__ part, float* __restrict__ mr, int C){
  int o = threadIdx.x;
  if (o < C){
    double s1=0.0, s2=0.0;
    for (int k=0;k<32;k++){ s1 += part[o*32+k]; s2 += part[(C+o)*32+k]; }
    const double n = (double)NPIX;
    double mean = s1/n;
    double var  = s2/n - mean*mean;
    mr[2*o]   = (float)mean;
    mr[2*o+1] = (float)(1.0/sqrt(var + (double)EPSF));
  }
}

// ======================= tiled MLP chain (unchanged from r9, passing) =======================
constexpr int XIN = 0;          // 6*68   = 408
constexpr int W0F = 408;        // 6*64   = 384
constexpr int B0F = 792;        // 64
constexpr int W1F = 856;        // 64*64  = 4096
constexpr int B1F = 4952;       // 64
constexpr int XBF = 5016;       // 64*68  = 4352
constexpr int SRF = 9368;       // 256  (f32 stats red, or u32 maxpool)
constexpr int W2F = 9624;       // 64*128 = 8192
constexpr int B2F = 17816;      // 128
constexpr int SM_SMALL = 9624;  // stages 1,2 (38.5 KB)
constexpr int SM_BIG   = 17944; // stages 3,4 (71.8 KB -> 2 blocks/CU)

template<int STAGE, bool STZ3, bool Z2IO>
__global__ __launch_bounds__(256,2) void mlp_kernel(
    const float* __restrict__ xyz, const float* __restrict__ pts,
    const float* __restrict__ nxyz, const int* __restrict__ grp,
    const float* __restrict__ w0, const float* __restrict__ b0,
    const float* __restrict__ mr1, const float* __restrict__ g0, const float* __restrict__ be0,
    const float* __restrict__ w1, const float* __restrict__ b1,
    const float* __restrict__ mr2, const float* __restrict__ g1, const float* __restrict__ be1,
    const float* __restrict__ w2, const float* __restrict__ b2,
    const float* __restrict__ mr3, const float* __restrict__ g2, const float* __restrict__ be2,
    double* __restrict__ part, float* __restrict__ out1,
    float* __restrict__ z2w, float* __restrict__ z3w)
{
  __shared__ float sm[(STAGE>=3)? SM_BIG : SM_SMALL];
  const int t   = threadIdx.x;
  const int blk = blockIdx.x;
  const int tx  = t & 15, ty = t >> 4;
  const int p0  = blk*64;
  const int slot = blk & 31;
  constexpr bool SKIP12 = (STAGE==3 && Z2IO);   // z2 sourced from global

  sm[SRF + t] = 0.0f;   // stats / maxpool slot (0.0f bits == 0u)

  if constexpr (!SKIP12){
    for (int i=t;i<384;i+=256){ int o=i/6, c=i-o*6; sm[W0F + c*64 + o] = w0[i]; }
    if (t<64) sm[B0F+t] = b0[t];
    if constexpr (STAGE>=2){
      for (int i=t;i<4096;i+=256){ int o=i&63, c=i>>6; sm[W1F + c*64 + o] = w1[o*64+c]; }
      if (t<64) sm[B1F+t] = b1[t];
    }
    for (int i=t;i<384;i+=256){
      int c=i>>6, px=i&63, p=p0+px, gid=p>>5, bb=p>>14;
      int idx = grp[p];
      float v;
      if (c<3) v = __fsub_rn(xyz[(size_t)bb*3*NN + c*NN + idx], nxyz[gid*3+c]);
      else     v = pts[(size_t)bb*3*NN + (c-3)*NN + idx];
      sm[XIN + c*68 + px] = v;
    }
  }
  if constexpr (STAGE>=3){
    for (int i=t;i<8192;i+=256){ int o=i&127, c=i>>7; sm[W2F + c*128 + o] = w2[o*64+c]; }
    if (t<128) sm[B2F+t] = b2[t];
  }
  __syncthreads();

  float z[4][4];
  if constexpr (SKIP12){
    // z2 (pre-norm) from global: same per-thread layout as the compute path
#pragma unroll
    for (int i=0;i<4;i++){
      float4 v = *(const float4*)&z2w[(size_t)(p0 + ty*4 + i)*64 + tx*4];
      z[i][0]=v.x; z[i][1]=v.y; z[i][2]=v.z; z[i][3]=v.w;
    }
  } else {
    // ---- layer 1: 6 -> 64 ----
#pragma unroll
    for (int i=0;i<4;i++)
#pragma unroll
      for (int j=0;j<4;j++) z[i][j]=0.0f;
#pragma unroll
    for (int k=0;k<6;k++){
      float4 xv = *(const float4*)&sm[XIN + k*68 + ty*4];
      float4 wv = *(const float4*)&sm[W0F + k*64 + tx*4];
      const float xs[4]={xv.x,xv.y,xv.z,xv.w};
      const float wsv[4]={wv.x,wv.y,wv.z,wv.w};
#pragma unroll
      for (int i=0;i<4;i++)
#pragma unroll
        for (int j=0;j<4;j++) z[i][j] = fmaf(xs[i], wsv[j], z[i][j]);
    }
#pragma unroll
    for (int i=0;i<4;i++)
#pragma unroll
      for (int j=0;j<4;j++) z[i][j] = __fadd_rn(z[i][j], sm[B0F + tx*4 + j]);

    if constexpr (STAGE==1){
#pragma unroll
      for (int j=0;j<4;j++){
        float s1=0.0f, s2=0.0f;
#pragma unroll
        for (int i=0;i<4;i++){ s1 = __fadd_rn(s1, z[i][j]); s2 = fmaf(z[i][j], z[i][j], s2); }
        atomicAdd(&sm[SRF + (tx*4+j)*2    ], s1);
        atomicAdd(&sm[SRF + (tx*4+j)*2 + 1], s2);
      }
      __syncthreads();
      if (t<128){ int ch=t>>1, m=t&1;
        atomicAdd(part + (size_t)((m? 64+ch : ch)*32 + slot), (double)sm[SRF+t]);
      }
      return;
    }

    // norm+relu(mr1) -> xbuf
#pragma unroll
    for (int j=0;j<4;j++){
      int ch = tx*4+j;
      float m=mr1[2*ch], r=mr1[2*ch+1], gg=g0[ch], bt=be0[ch];
      float4 o;
      o.x = fmaxf(fmaf(__fmul_rn(__fsub_rn(z[0][j],m),r), gg, bt), 0.0f);
      o.y = fmaxf(fmaf(__fmul_rn(__fsub_rn(z[1][j],m),r), gg, bt), 0.0f);
      o.z = fmaxf(fmaf(__fmul_rn(__fsub_rn(z[2][j],m),r), gg, bt), 0.0f);
      o.w = fmaxf(fmaf(__fmul_rn(__fsub_rn(z[3][j],m),r), gg, bt), 0.0f);
      *(float4*)&sm[XBF + ch*68 + ty*4] = o;
    }
    __syncthreads();

    // ---- layer 2: 64 -> 64 ----
#pragma unroll
    for (int i=0;i<4;i++)
#pragma unroll
      for (int j=0;j<4;j++) z[i][j]=0.0f;
#pragma unroll 8
    for (int k=0;k<64;k++){
      float4 xv = *(const float4*)&sm[XBF + k*68 + ty*4];
      float4 wv = *(const float4*)&sm[W1F + k*64 + tx*4];
      const float xs[4]={xv.x,xv.y,xv.z,xv.w};
      const float wsv[4]={wv.x,wv.y,wv.z,wv.w};
#pragma unroll
      for (int i=0;i<4;i++)
#pragma unroll
        for (int j=0;j<4;j++) z[i][j] = fmaf(xs[i], wsv[j], z[i][j]);
    }
#pragma unroll
    for (int i=0;i<4;i++)
#pragma unroll
      for (int j=0;j<4;j++) z[i][j] = __fadd_rn(z[i][j], sm[B1F + tx*4 + j]);

    if constexpr (STAGE==2){
      if constexpr (Z2IO){
#pragma unroll
        for (int i=0;i<4;i++)
          *(float4*)&z2w[(size_t)(p0 + ty*4 + i)*64 + tx*4]
              = make_float4(z[i][0], z[i][1], z[i][2], z[i][3]);
      }
#pragma unroll
      for (int j=0;j<4;j++){
        float s1=0.0f, s2=0.0f;
#pragma unroll
        for (int i=0;i<4;i++){ s1 = __fadd_rn(s1, z[i][j]); s2 = fmaf(z[i][j], z[i][j], s2); }
        atomicAdd(&sm[SRF + (tx*4+j)*2    ], s1);
        atomicAdd(&sm[SRF + (tx*4+j)*2 + 1], s2);
      }
      __syncthreads();
      if (t<128){ int ch=t>>1, m=t&1;
        atomicAdd(part + (size_t)((m? 64+ch : ch)*32 + slot), (double)sm[SRF+t]);
      }
      return;
    }
  }

  if constexpr (STAGE>=3){
    __syncthreads();   // WAR guard on XBF (harmless in SKIP12 path)
#pragma unroll
    for (int j=0;j<4;j++){
      int ch = tx*4+j;
      float m=mr2[2*ch], r=mr2[2*ch+1], gg=g1[ch], bt=be1[ch];
      float4 o;
      o.x = fmaxf(fmaf(__fmul_rn(__fsub_rn(z[0][j],m),r), gg, bt), 0.0f);
      o.y = fmaxf(fmaf(__fmul_rn(__fsub_rn(z[1][j],m),r), gg, bt), 0.0f);
      o.z = fmaxf(fmaf(__fmul_rn(__fsub_rn(z[2][j],m),r), gg, bt), 0.0f);
      o.w = fmaxf(fmaf(__fmul_rn(__fsub_rn(z[3][j],m),r), gg, bt), 0.0f);
      *(float4*)&sm[XBF + ch*68 + ty*4] = o;
    }
    __syncthreads();

    // ---- layer 3: 64 -> 128 ----
    float a3[4][8];
#pragma unroll
    for (int i=0;i<4;i++)
#pragma unroll
      for (int j=0;j<8;j++) a3[i][j]=0.0f;
#pragma unroll 4
    for (int k=0;k<64;k++){
      float4 xv  = *(const float4*)&sm[XBF + k*68  + ty*4];
      float4 wv0 = *(const float4*)&sm[W2F + k*128 + tx*4];
      float4 wv1 = *(const float4*)&sm[W2F + k*128 + 64 + tx*4];
      const float xs[4]={xv.x,xv.y,xv.z,xv.w};
      const float wsv[8]={wv0.x,wv0.y,wv0.z,wv0.w, wv1.x,wv1.y,wv1.z,wv1.w};
#pragma unroll
      for (int i=0;i<4;i++)
#pragma unroll
        for (int j=0;j<8;j++) a3[i][j] = fmaf(xs[i], wsv[j], a3[i][j]);
    }
#pragma unroll
    for (int i=0;i<4;i++)
#pragma unroll
      for (int j=0;j<8;j++){
        int ch = (j<4)? (tx*4+j) : (64+tx*4+(j-4));
        a3[i][j] = __fadd_rn(a3[i][j], sm[B2F + ch]);
      }

    if constexpr (STAGE==3){
      if constexpr (STZ3){
#pragma unroll
        for (int i=0;i<4;i++){
          size_t p = (size_t)(p0 + ty*4 + i)*128;
          *(float4*)&z3w[p + tx*4]      = make_float4(a3[i][0],a3[i][1],a3[i][2],a3[i][3]);
          *(float4*)&z3w[p + 64 + tx*4] = make_float4(a3[i][4],a3[i][5],a3[i][6],a3[i][7]);
        }
      }
#pragma unroll
      for (int j=0;j<8;j++){
        int ch = (j<4)? (tx*4+j) : (64+tx*4+(j-4));
        float s1=0.0f, s2=0.0f;
#pragma unroll
        for (int i=0;i<4;i++){ s1 = __fadd_rn(s1, a3[i][j]); s2 = fmaf(a3[i][j], a3[i][j], s2); }
        atomicAdd(&sm[SRF + ch*2    ], s1);
        atomicAdd(&sm[SRF + ch*2 + 1], s2);
      }
      __syncthreads();
      { int ch=t>>1, m=t&1;
        atomicAdd(part + (size_t)((m? 128+ch : ch)*32 + slot), (double)sm[SRF+t]);
      }
      return;
    }

    if constexpr (STAGE==4){
      const int grp_l = ty>>3;
      unsigned* omax = (unsigned*)sm;
#pragma unroll
      for (int j=0;j<8;j++){
        int ch = (j<4)? (tx*4+j) : (64+tx*4+(j-4));
        float m=mr3[2*ch], r=mr3[2*ch+1], gg=g2[ch], bt=be2[ch];
        float vmax=0.0f;
#pragma unroll
        for (int i=0;i<4;i++){
          float v = fmaxf(fmaf(__fmul_rn(__fsub_rn(a3[i][j],m),r), gg, bt), 0.0f);
          vmax = fmaxf(vmax, v);
        }
        atomicMax(&omax[SRF + grp_l*128 + ch], __float_as_uint(vmax));
      }
      __syncthreads();
      { int g = t>>7, o = t&127;
        int gid = blk*2 + g, bb = gid>>9, s = gid&511;
        out1[((size_t)(bb*128+o))*512 + s] = __uint_as_float(omax[SRF + t]);
      }
    }
  }
}

// ======================= maxpool reader (unchanged, passing) =======================
__global__ __launch_bounds__(256) void maxpool_kernel(const float* __restrict__ z3,
        const float* __restrict__ mr3, const float* __restrict__ g2,
        const float* __restrict__ be2, float* __restrict__ out1){
  const int t = threadIdx.x;
  const int g = blockIdx.x*2 + (t>>7);     // group id (b*SS+s)
  const int o = t & 127;
  const int bb = g >> 9, s = g & 511;
  const float* zp = z3 + (size_t)g*KK*128 + o;
  float m=mr3[2*o], r=mr3[2*o+1], gg=g2[o], bt=be2[o];
  float mx = 0.0f;                         // relu outputs are >= 0
#pragma unroll 8
  for (int k=0;k<KK;k++){
    float v = fmaxf(fmaf(__fmul_rn(__fsub_rn(zp[(size_t)k*128],m),r), gg, bt), 0.0f);
    mx = fmaxf(mx, v);
  }
  out1[((size_t)(bb*128+o))*SS + s] = mx;
}

// ======================= launch =======================
extern "C" void kernel_launch(void* const* d_in, const int* in_sizes, int n_in,
                              void* d_out, int out_size, void* d_ws, size_t ws_size,
                              hipStream_t stream){
  const float* xyz = (const float*)d_in[0];
  const float* pts = (const float*)d_in[1];
  const float* w0  = (const float*)d_in[2];  const float* b0  = (const float*)d_in[3];
  const float* g0  = (const float*)d_in[4];  const float* be0 = (const float*)d_in[5];
  const float* w1  = (const float*)d_in[6];  const float* b1  = (const float*)d_in[7];
  const float* g1  = (const float*)d_in[8];  const float* be1 = (const float*)d_in[9];
  const float* w2  = (const float*)d_in[10]; const float* b2  = (const float*)d_in[11];
  const float* g2  = (const float*)d_in[12]; const float* be2 = (const float*)d_in[13];

  float* out  = (float*)d_out;
  float* out1 = out + BB*3*SS;
  char*  ws   = (char*)d_ws;

  float*  nxyz = (float*)(ws + OFF_NXYZ);
  int*    grp  = (int*)  (ws + OFF_GRP);
  double* p1   = (double*)(ws + OFF_P1);
  double* p2   = (double*)(ws + OFF_P2);
  double* p3   = (double*)(ws + OFF_P3);
  float*  mr1  = (float*)(ws + OFF_MR1);
  float*  mr2  = (float*)(ws + OFF_MR2);
  float*  mr3  = (float*)(ws + OFF_MR3);
  float*  z3w  = (float*)(ws + OFF_Z3);
  float*  z2w  = (float*)(ws + OFF_Z2);

  const bool stz3 = (ws_size >= NEED_Z3);
  const bool stz2 = (ws_size >= NEED_Z2);   // implies stz3

  // p1/p2/p3 zeroing folded into fps_kernel (replaces hipMemsetAsync)
  fps_kernel <<<BB, 512, 0, stream>>>(xyz, out, nxyz, p1);
  ball_kernel<<<NGRP*64/256, 256, 0, stream>>>(xyz, nxyz, grp);

#define MLP_ARGS xyz, pts, nxyz, grp, w0, b0, mr1, g0, be0, w1, b1, mr2, g1, be1, w2, b2, mr3, g2, be2
  mlp_kernel<1,false,false><<<NPIX/64, 256, 0, stream>>>(MLP_ARGS, p1, out1, z2w, z3w);
  finalize_kernel<<<1,128,0,stream>>>(p1, mr1, 64);
  if (stz2) mlp_kernel<2,false,true ><<<NPIX/64, 256, 0, stream>>>(MLP_ARGS, p2, out1, z2w, z3w);
  else      mlp_kernel<2,false,false><<<NPIX/64, 256, 0, stream>>>(MLP_ARGS, p2, out1, z2w, z3w);
  finalize_kernel<<<1,128,0,stream>>>(p2, mr2, 64);
  if (stz2)      mlp_kernel<3,true ,true ><<<NPIX/64, 256, 0, stream>>>(MLP_ARGS, p3, out1, z2w, z3w);
  else if (stz3) mlp_kernel<3,true ,false><<<NPIX/64, 256, 0, stream>>>(MLP_ARGS, p3, out1, z2w, z3w);
  else           mlp_kernel<3,false,false><<<NPIX/64, 256, 0, stream>>>(MLP_ARGS, p3, out1, z2w, z3w);
  finalize_kernel<<<1,128,0,stream>>>(p3, mr3, 128);
  if (stz3) maxpool_kernel<<<NGRP/2, 256, 0, stream>>>(z3w, mr3, g2, be2, out1);
  else      mlp_kernel<4,false,false><<<NPIX/64, 256, 0, stream>>>(MLP_ARGS, p3, out1, z2w, z3w);
#undef MLP_ARGS
}

// Round 13
// 791.870 us; speedup vs baseline: 1.3507x; 1.0108x over previous
//
#include <hip/hip_runtime.h>
#include <math.h>

#define BB 16
#define NN 4096
#define SS 512
#define KK 32
#define NPIX (BB*SS*KK)          /* 262144 pixels (b,s,k) */
#define NGRP (BB*SS)             /* 8192 groups */

static constexpr float R2F  = (float)0.16000000000000003;  // RADIUS**2 as f32
static constexpr float EPSF = 1e-5f;

// ---------------- workspace layout (bytes) ----------------
constexpr size_t OFF_NXYZ = 0;                     // B*S*3 f32  = 98304
constexpr size_t OFF_GRP  = 98304;                 // B*S*NS i32 = 1048576
constexpr size_t OFF_P1   = 98304 + 1048576;       // 2*64*32 f64  = 32768
constexpr size_t OFF_P2   = OFF_P1 + 32768;
constexpr size_t OFF_P3   = OFF_P2 + 32768;        // 2*128*32 f64 = 65536
constexpr size_t OFF_MR1  = OFF_P3 + 65536;        // 64*2 f32
constexpr size_t OFF_MR2  = OFF_MR1 + 512;
constexpr size_t OFF_MR3  = OFF_MR2 + 512;         // 128*2 f32
constexpr size_t OFF_Z2   = 2*1024*1024;           // z2 now lives here (z3 gone)
constexpr size_t Z2SZ     = (size_t)NPIX*64*4;     // 67108864
constexpr size_t OFF_POOL = OFF_Z2 + Z2SZ;
constexpr size_t POOLSZ   = (size_t)NGRP*256*4;    // 8388608 (max+min per gid,ch)
constexpr size_t NEED_POOL= OFF_POOL + POOLSZ;     // ~77MB (ws measured >=203MB)

// Packed-u64 DPP max step with LITERAL dpp ctrl (builtin requires constant).
// key = (dist_bits<<32)|~idx; u64 max == (max dist, lowest index).
#define DPP_U64MAX(key, ctrl) {                                                  \
    unsigned _hi = (unsigned)((key) >> 32), _lo = (unsigned)(key);               \
    unsigned _h2 = (unsigned)__builtin_amdgcn_update_dpp((int)_hi,(int)_hi,(ctrl),0xf,0xf,false); \
    unsigned _l2 = (unsigned)__builtin_amdgcn_update_dpp((int)_lo,(int)_lo,(ctrl),0xf,0xf,false); \
    unsigned long long _o = ((unsigned long long)_h2 << 32) | _l2;               \
    (key) = (_o > (key)) ? _o : (key); }

// Monotone signed-float <-> uint mapping (uint order == float order).
__device__ __forceinline__ unsigned encf(float f){
  unsigned u = __float_as_uint(f);
  return u ^ (0x80000000u | (unsigned)((int)u >> 31));
}
__device__ __forceinline__ float decf(unsigned e){
  return (e & 0x80000000u) ? __uint_as_float(e ^ 0x80000000u) : __uint_as_float(~e);
}

// ======================= FPS (r12-measured 332us, unchanged) =======================
__global__ __launch_bounds__(512) void fps_kernel(const float* __restrict__ xyz,
        float* __restrict__ out0, float* __restrict__ nxyz, double* __restrict__ pzero){
  const int b = blockIdx.x;
  const float* xb = xyz + (size_t)b*3*NN;
  __shared__ float4 pt4[NN];                       // 64 KB
  __shared__ __align__(16) unsigned long long skey[2][8];
  __shared__ int hist[SS];
  const int t = threadIdx.x;
  const int lane = t & 63, wv = t >> 6;            // wv in [0,8)
  // zero stats partials p1+p2+p3 = 131072 B = 16384 f64 (16 blocks x 512 thr)
  for (int i = b*512 + t; i < 16384; i += 16*512) pzero[i] = 0.0;
  float rx[8], ry[8], rz[8], rd[8];
#pragma unroll
  for (int j=0;j<8;j++){
    int i = t + 512*j;
    float x = xb[i], y = xb[NN+i], z = xb[2*NN+i];
    rx[j]=x; ry[j]=y; rz[j]=z;
    pt4[i] = make_float4(x,y,z,0.0f);
    rd[j]=1e10f;
  }
  __syncthreads();
  int far = 0;
  for (int s=0;s<SS;s++){
    const int buf = s & 1;
    float4 c = pt4[far];
    if (t==0) hist[s] = far;
    float bv = -1.0f; int bi = 0;
#pragma unroll
    for (int j=0;j<8;j++){
      float dx=__fsub_rn(rx[j],c.x), dy=__fsub_rn(ry[j],c.y), dz=__fsub_rn(rz[j],c.z);
      float d2=__fadd_rn(__fadd_rn(__fmul_rn(dx,dx),__fmul_rn(dy,dy)),__fmul_rn(dz,dz));
      float nd=fminf(rd[j],d2);
      rd[j]=nd;
      if (nd>bv){bv=nd;bi=t+512*j;}   // indices ascend with j -> first-max kept
    }
    unsigned long long key = ((unsigned long long)(unsigned)__float_as_int(bv) << 32)
                           | (unsigned)(~(unsigned)bi);
    DPP_U64MAX(key,0x111); DPP_U64MAX(key,0x112); DPP_U64MAX(key,0x114);
    DPP_U64MAX(key,0x118); DPP_U64MAX(key,0x142); DPP_U64MAX(key,0x143);
    if (lane==63) skey[buf][wv] = key;
    __syncthreads();
    unsigned long long k0=skey[buf][0], k1=skey[buf][1], k2=skey[buf][2], k3=skey[buf][3];
    unsigned long long k4=skey[buf][4], k5=skey[buf][5], k6=skey[buf][6], k7=skey[buf][7];
    unsigned long long m01=(k0>k1)?k0:k1, m23=(k2>k3)?k2:k3;
    unsigned long long m45=(k4>k5)?k4:k5, m67=(k6>k7)?k6:k7;
    unsigned long long mA=(m01>m23)?m01:m23, mB=(m45>m67)?m45:m67;
    unsigned long long m =(mA>mB)?mA:mB;
    far = (int)(~(unsigned)(m & 0xFFFFFFFFull));
  }
  __syncthreads();
  {
    int idx = hist[t];
    float4 c = pt4[idx];
    int gid = b*SS + t;
    nxyz[gid*3+0]=c.x; nxyz[gid*3+1]=c.y; nxyz[gid*3+2]=c.z;
    out0[(b*3+0)*SS+t]=c.x; out0[(b*3+1)*SS+t]=c.y; out0[(b*3+2)*SS+t]=c.z;
  }
}

// ======================= ball query (unchanged, passing) =======================
__global__ __launch_bounds__(256) void ball_kernel(const float* __restrict__ xyz,
        const float* __restrict__ nxyz, int* __restrict__ grp){
  const int gw   = (blockIdx.x*256 + threadIdx.x) >> 6;
  const int lane = threadIdx.x & 63;
  if (gw >= NGRP) return;
  const int b = gw / SS;
  const float* xb = xyz + (size_t)b*3*NN;
  const float nx=nxyz[gw*3+0], ny=nxyz[gw*3+1], nz=nxyz[gw*3+2];
  const float sn = __fadd_rn(__fadd_rn(__fmul_rn(nx,nx),__fmul_rn(ny,ny)),__fmul_rn(nz,nz));
  int cnt=0, first=-1;
  int* g = grp + (size_t)gw*KK;
  for (int c=0;c<NN/64 && cnt<KK;c++){
    int i=c*64+lane;
    float x=xb[i], y=xb[NN+i], z=xb[2*NN+i];
    float sxx=__fadd_rn(__fadd_rn(__fmul_rn(x,x),__fmul_rn(y,y)),__fmul_rn(z,z));
    float dot=__fadd_rn(__fadd_rn(__fmul_rn(nx,x),__fmul_rn(ny,y)),__fmul_rn(nz,z));
    float sqr=__fsub_rn(__fadd_rn(sn,sxx),__fmul_rn(2.0f,dot));
    bool m = (sqr <= R2F);
    unsigned long long mask = __ballot(m);
    if (m){
      int pos = cnt + __popcll(mask & ((1ull<<lane)-1ull));
      if (pos < KK) g[pos] = i;
    }
    if (first<0 && mask) first = c*64 + (__ffsll((long long)mask) - 1);
    cnt += __popcll(mask);
  }
  if (cnt < KK && lane >= cnt && lane < KK) g[lane] = first;
}

// ======================= finalize (unchanged) =======================
__global__ void finalize_kernel(const double* __restrict__ part, float* __restrict__ mr, int C){
  int o = threadIdx.x;
  if (o < C){
    double s1=0.0, s2=0.0;
    for (int k=0;k<32;k++){ s1 += part[o*32+k]; s2 += part[(C+o)*32+k]; }
    const double n = (double)NPIX;
    double mean = s1/n;
    double var  = s2/n - mean*mean;
    mr[2*o]   = (float)mean;
    mr[2*o+1] = (float)(1.0/sqrt(var + (double)EPSF));
  }
}

// ======================= tiled MLP chain =======================
// POOL (stage 3): instead of storing 134MB z3 for a maxpool re-read, pool RAW
// z3 max&min per (group,channel) in LDS (monotone uint encoding, atomicMax/Min)
// and store 8MB. Exactness: y = relu(fmaf((z-m)*r, g, beta)) is a composition
// of correctly-rounded weakly-monotone ops in z (direction = sign(g), r>0), and
// max commutes exactly with weakly-monotone maps:
// max_k y(z_k) = max(y(max_k z_k), y(min_k z_k)) for ANY sign of g.
constexpr int XIN = 0;          // 6*68   = 408
constexpr int W0F = 408;        // 6*64   = 384
constexpr int B0F = 792;        // 64
constexpr int W1F = 856;        // 64*64  = 4096
constexpr int B1F = 4952;       // 64
constexpr int XBF = 5016;       // 64*68  = 4352
constexpr int SRF = 9368;       // 256  (f32 stats red, or u32 maxpool)
constexpr int W2F = 9624;       // 64*128 = 8192
constexpr int B2F = 17816;      // 128
constexpr int POOLU = 17944;    // 512 u32: [max 2x128][min 2x128]
constexpr int SM_SMALL = 9624;  // stages 1,2 (38.5 KB)
constexpr int SM_BIG   = 18456; // stages 3,4 (73.8 KB -> 2 blocks/CU)

template<int STAGE, bool POOL, bool Z2IO>
__global__ __launch_bounds__(256,2) void mlp_kernel(
    const float* __restrict__ xyz, const float* __restrict__ pts,
    const float* __restrict__ nxyz, const int* __restrict__ grp,
    const float* __restrict__ w0, const float* __restrict__ b0,
    const float* __restrict__ mr1, const float* __restrict__ g0, const float* __restrict__ be0,
    const float* __restrict__ w1, const float* __restrict__ b1,
    const float* __restrict__ mr2, const float* __restrict__ g1, const float* __restrict__ be1,
    const float* __restrict__ w2, const float* __restrict__ b2,
    const float* __restrict__ mr3, const float* __restrict__ g2, const float* __restrict__ be2,
    double* __restrict__ part, float* __restrict__ out1,
    float* __restrict__ z2w, unsigned* __restrict__ poolg)
{
  __shared__ float sm[(STAGE>=3)? SM_BIG : SM_SMALL];
  const int t   = threadIdx.x;
  const int blk = blockIdx.x;
  const int tx  = t & 15, ty = t >> 4;
  const int p0  = blk*64;
  const int slot = blk & 31;
  constexpr bool SKIP12 = (STAGE==3 && Z2IO);   // z2 sourced from global

  sm[SRF + t] = 0.0f;   // stats slot
  if constexpr (STAGE==3 && POOL){
    unsigned* pu = (unsigned*)sm;
    pu[POOLU + t]       = 0u;           // max accumulator (enc order: 0 = lowest)
    pu[POOLU + 256 + t] = 0xFFFFFFFFu;  // min accumulator (enc order: ~0 = highest)
  }

  if constexpr (!SKIP12){
    for (int i=t;i<384;i+=256){ int o=i/6, c=i-o*6; sm[W0F + c*64 + o] = w0[i]; }
    if (t<64) sm[B0F+t] = b0[t];
    if constexpr (STAGE>=2){
      for (int i=t;i<4096;i+=256){ int o=i&63, c=i>>6; sm[W1F + c*64 + o] = w1[o*64+c]; }
      if (t<64) sm[B1F+t] = b1[t];
    }
    for (int i=t;i<384;i+=256){
      int c=i>>6, px=i&63, p=p0+px, gid=p>>5, bb=p>>14;
      int idx = grp[p];
      float v;
      if (c<3) v = __fsub_rn(xyz[(size_t)bb*3*NN + c*NN + idx], nxyz[gid*3+c]);
      else     v = pts[(size_t)bb*3*NN + (c-3)*NN + idx];
      sm[XIN + c*68 + px] = v;
    }
  }
  if constexpr (STAGE>=3){
    for (int i=t;i<8192;i+=256){ int o=i&127, c=i>>7; sm[W2F + c*128 + o] = w2[o*64+c]; }
    if (t<128) sm[B2F+t] = b2[t];
  }
  __syncthreads();

  float z[4][4];
  if constexpr (SKIP12){
#pragma unroll
    for (int i=0;i<4;i++){
      float4 v = *(const float4*)&z2w[(size_t)(p0 + ty*4 + i)*64 + tx*4];
      z[i][0]=v.x; z[i][1]=v.y; z[i][2]=v.z; z[i][3]=v.w;
    }
  } else {
    // ---- layer 1: 6 -> 64 ----
#pragma unroll
    for (int i=0;i<4;i++)
#pragma unroll
      for (int j=0;j<4;j++) z[i][j]=0.0f;
#pragma unroll
    for (int k=0;k<6;k++){
      float4 xv = *(const float4*)&sm[XIN + k*68 + ty*4];
      float4 wv = *(const float4*)&sm[W0F + k*64 + tx*4];
      const float xs[4]={xv.x,xv.y,xv.z,xv.w};
      const float wsv[4]={wv.x,wv.y,wv.z,wv.w};
#pragma unroll
      for (int i=0;i<4;i++)
#pragma unroll
        for (int j=0;j<4;j++) z[i][j] = fmaf(xs[i], wsv[j], z[i][j]);
    }
#pragma unroll
    for (int i=0;i<4;i++)
#pragma unroll
      for (int j=0;j<4;j++) z[i][j] = __fadd_rn(z[i][j], sm[B0F + tx*4 + j]);

    if constexpr (STAGE==1){
#pragma unroll
      for (int j=0;j<4;j++){
        float s1=0.0f, s2=0.0f;
#pragma unroll
        for (int i=0;i<4;i++){ s1 = __fadd_rn(s1, z[i][j]); s2 = fmaf(z[i][j], z[i][j], s2); }
        atomicAdd(&sm[SRF + (tx*4+j)*2    ], s1);
        atomicAdd(&sm[SRF + (tx*4+j)*2 + 1], s2);
      }
      __syncthreads();
      if (t<128){ int ch=t>>1, m=t&1;
        atomicAdd(part + (size_t)((m? 64+ch : ch)*32 + slot), (double)sm[SRF+t]);
      }
      return;
    }

    // norm+relu(mr1) -> xbuf
#pragma unroll
    for (int j=0;j<4;j++){
      int ch = tx*4+j;
      float m=mr1[2*ch], r=mr1[2*ch+1], gg=g0[ch], bt=be0[ch];
      float4 o;
      o.x = fmaxf(fmaf(__fmul_rn(__fsub_rn(z[0][j],m),r), gg, bt), 0.0f);
      o.y = fmaxf(fmaf(__fmul_rn(__fsub_rn(z[1][j],m),r), gg, bt), 0.0f);
      o.z = fmaxf(fmaf(__fmul_rn(__fsub_rn(z[2][j],m),r), gg, bt), 0.0f);
      o.w = fmaxf(fmaf(__fmul_rn(__fsub_rn(z[3][j],m),r), gg, bt), 0.0f);
      *(float4*)&sm[XBF + ch*68 + ty*4] = o;
    }
    __syncthreads();

    // ---- layer 2: 64 -> 64 ----
#pragma unroll
    for (int i=0;i<4;i++)
#pragma unroll
      for (int j=0;j<4;j++) z[i][j]=0.0f;
#pragma unroll 8
    for (int k=0;k<64;k++){
      float4 xv = *(const float4*)&sm[XBF + k*68 + ty*4];
      float4 wv = *(const float4*)&sm[W1F + k*64 + tx*4];
      const float xs[4]={xv.x,xv.y,xv.z,xv.w};
      const float wsv[4]={wv.x,wv.y,wv.z,wv.w};
#pragma unroll
      for (int i=0;i<4;i++)
#pragma unroll
        for (int j=0;j<4;j++) z[i][j] = fmaf(xs[i], wsv[j], z[i][j]);
    }
#pragma unroll
    for (int i=0;i<4;i++)
#pragma unroll
      for (int j=0;j<4;j++) z[i][j] = __fadd_rn(z[i][j], sm[B1F + tx*4 + j]);

    if constexpr (STAGE==2){
      if constexpr (Z2IO){
#pragma unroll
        for (int i=0;i<4;i++)
          *(float4*)&z2w[(size_t)(p0 + ty*4 + i)*64 + tx*4]
              = make_float4(z[i][0], z[i][1], z[i][2], z[i][3]);
      }
#pragma unroll
      for (int j=0;j<4;j++){
        float s1=0.0f, s2=0.0f;
#pragma unroll
        for (int i=0;i<4;i++){ s1 = __fadd_rn(s1, z[i][j]); s2 = fmaf(z[i][j], z[i][j], s2); }
        atomicAdd(&sm[SRF + (tx*4+j)*2    ], s1);
        atomicAdd(&sm[SRF + (tx*4+j)*2 + 1], s2);
      }
      __syncthreads();
      if (t<128){ int ch=t>>1, m=t&1;
        atomicAdd(part + (size_t)((m? 64+ch : ch)*32 + slot), (double)sm[SRF+t]);
      }
      return;
    }
  }

  if constexpr (STAGE>=3){
    __syncthreads();   // WAR guard on XBF (harmless in SKIP12 path)
#pragma unroll
    for (int j=0;j<4;j++){
      int ch = tx*4+j;
      float m=mr2[2*ch], r=mr2[2*ch+1], gg=g1[ch], bt=be1[ch];
      float4 o;
      o.x = fmaxf(fmaf(__fmul_rn(__fsub_rn(z[0][j],m),r), gg, bt), 0.0f);
      o.y = fmaxf(fmaf(__fmul_rn(__fsub_rn(z[1][j],m),r), gg, bt), 0.0f);
      o.z = fmaxf(fmaf(__fmul_rn(__fsub_rn(z[2][j],m),r), gg, bt), 0.0f);
      o.w = fmaxf(fmaf(__fmul_rn(__fsub_rn(z[3][j],m),r), gg, bt), 0.0f);
      *(float4*)&sm[XBF + ch*68 + ty*4] = o;
    }
    __syncthreads();

    // ---- layer 3: 64 -> 128 ----
    float a3[4][8];
#pragma unroll
    for (int i=0;i<4;i++)
#pragma unroll
      for (int j=0;j<8;j++) a3[i][j]=0.0f;
#pragma unroll 4
    for (int k=0;k<64;k++){
      float4 xv  = *(const float4*)&sm[XBF + k*68  + ty*4];
      float4 wv0 = *(const float4*)&sm[W2F + k*128 + tx*4];
      float4 wv1 = *(const float4*)&sm[W2F + k*128 + 64 + tx*4];
      const float xs[4]={xv.x,xv.y,xv.z,xv.w};
      const float wsv[8]={wv0.x,wv0.y,wv0.z,wv0.w, wv1.x,wv1.y,wv1.z,wv1.w};
#pragma unroll
      for (int i=0;i<4;i++)
#pragma unroll
        for (int j=0;j<8;j++) a3[i][j] = fmaf(xs[i], wsv[j], a3[i][j]);
    }
#pragma unroll
    for (int i=0;i<4;i++)
#pragma unroll
      for (int j=0;j<8;j++){
        int ch = (j<4)? (tx*4+j) : (64+tx*4+(j-4));
        a3[i][j] = __fadd_rn(a3[i][j], sm[B2F + ch]);
      }

    if constexpr (STAGE==3){
      if constexpr (POOL){
        unsigned* pu = (unsigned*)sm;
        const int gl = ty>>3;
#pragma unroll
        for (int j=0;j<8;j++){
          int ch = (j<4)? (tx*4+j) : (64+tx*4+(j-4));
          float mx = fmaxf(fmaxf(a3[0][j],a3[1][j]), fmaxf(a3[2][j],a3[3][j]));
          float mn = fminf(fminf(a3[0][j],a3[1][j]), fminf(a3[2][j],a3[3][j]));
          atomicMax(&pu[POOLU + gl*128 + ch], encf(mx));
          atomicMin(&pu[POOLU + 256 + gl*128 + ch], encf(mn));
        }
      }
#pragma unroll
      for (int j=0;j<8;j++){
        int ch = (j<4)? (tx*4+j) : (64+tx*4+(j-4));
        float s1=0.0f, s2=0.0f;
#pragma unroll
        for (int i=0;i<4;i++){ s1 = __fadd_rn(s1, a3[i][j]); s2 = fmaf(a3[i][j], a3[i][j], s2); }
        atomicAdd(&sm[SRF + ch*2    ], s1);
        atomicAdd(&sm[SRF + ch*2 + 1], s2);
      }
      __syncthreads();
      { int ch=t>>1, m=t&1;
        atomicAdd(part + (size_t)((m? 128+ch : ch)*32 + slot), (double)sm[SRF+t]);
      }
      if constexpr (POOL){
        unsigned* pu = (unsigned*)sm;
        const int gl2 = t>>7, ch2 = t&127;
        size_t base = (size_t)(blk*2+gl2)*256;
        poolg[base + ch2]       = pu[POOLU + gl2*128 + ch2];
        poolg[base + 128 + ch2] = pu[POOLU + 256 + gl2*128 + ch2];
      }
      return;
    }

    if constexpr (STAGE==4){
      const int grp_l = ty>>3;
      unsigned* omax = (unsigned*)sm;
#pragma unroll
      for (int j=0;j<8;j++){
        int ch = (j<4)? (tx*4+j) : (64+tx*4+(j-4));
        float m=mr3[2*ch], r=mr3[2*ch+1], gg=g2[ch], bt=be2[ch];
        float vmax=0.0f;
#pragma unroll
        for (int i=0;i<4;i++){
          float v = fmaxf(fmaf(__fmul_rn(__fsub_rn(a3[i][j],m),r), gg, bt), 0.0f);
          vmax = fmaxf(vmax, v);
        }
        atomicMax(&omax[SRF + grp_l*128 + ch], __float_as_uint(vmax));
      }
      __syncthreads();
      { int g = t>>7, o = t&127;
        int gid = blk*2 + g, bb = gid>>9, s = gid&511;
        out1[((size_t)(bb*128+o))*512 + s] = __uint_as_float(omax[SRF + t]);
      }
    }
  }
}

// ======================= pooled-minmax finalizer (replaces 134MB maxpool) ===========
__global__ __launch_bounds__(256) void pool_kernel(const unsigned* __restrict__ poolg,
        const float* __restrict__ mr3, const float* __restrict__ g2,
        const float* __restrict__ be2, float* __restrict__ out1){
  const int t = threadIdx.x;
  const int gl = t>>7, ch = t&127;
  const int gid = blockIdx.x*2 + gl;            // b*SS+s
  const int bb = gid>>9, s = gid&511;
  float fmx = decf(poolg[(size_t)gid*256 + ch]);
  float fmn = decf(poolg[(size_t)gid*256 + 128 + ch]);
  float m=mr3[2*ch], r=mr3[2*ch+1], gg=g2[ch], bt=be2[ch];
  float ya = fmaxf(fmaf(__fmul_rn(__fsub_rn(fmx,m),r), gg, bt), 0.0f);
  float yb = fmaxf(fmaf(__fmul_rn(__fsub_rn(fmn,m),r), gg, bt), 0.0f);
  out1[((size_t)(bb*128+ch))*SS + s] = fmaxf(ya, yb);
}

// ======================= launch =======================
extern "C" void kernel_launch(void* const* d_in, const int* in_sizes, int n_in,
                              void* d_out, int out_size, void* d_ws, size_t ws_size,
                              hipStream_t stream){
  const float* xyz = (const float*)d_in[0];
  const float* pts = (const float*)d_in[1];
  const float* w0  = (const float*)d_in[2];  const float* b0  = (const float*)d_in[3];
  const float* g0  = (const float*)d_in[4];  const float* be0 = (const float*)d_in[5];
  const float* w1  = (const float*)d_in[6];  const float* b1  = (const float*)d_in[7];
  const float* g1  = (const float*)d_in[8];  const float* be1 = (const float*)d_in[9];
  const float* w2  = (const float*)d_in[10]; const float* b2  = (const float*)d_in[11];
  const float* g2  = (const float*)d_in[12]; const float* be2 = (const float*)d_in[13];

  float* out  = (float*)d_out;
  float* out1 = out + BB*3*SS;
  char*  ws   = (char*)d_ws;

  float*    nxyz  = (float*)(ws + OFF_NXYZ);
  int*      grp   = (int*)  (ws + OFF_GRP);
  double*   p1    = (double*)(ws + OFF_P1);
  double*   p2    = (double*)(ws + OFF_P2);
  double*   p3    = (double*)(ws + OFF_P3);
  float*    mr1   = (float*)(ws + OFF_MR1);
  float*    mr2   = (float*)(ws + OFF_MR2);
  float*    mr3   = (float*)(ws + OFF_MR3);
  float*    z2w   = (float*)(ws + OFF_Z2);
  unsigned* poolg = (unsigned*)(ws + OFF_POOL);

  const bool pool = (ws_size >= NEED_POOL);   // ~77MB; measured ws >= 203MB

  // p1/p2/p3 zeroing folded into fps_kernel (replaces hipMemsetAsync)
  fps_kernel <<<BB, 512, 0, stream>>>(xyz, out, nxyz, p1);
  ball_kernel<<<NGRP*64/256, 256, 0, stream>>>(xyz, nxyz, grp);

#define MLP_ARGS xyz, pts, nxyz, grp, w0, b0, mr1, g0, be0, w1, b1, mr2, g1, be1, w2, b2, mr3, g2, be2
  mlp_kernel<1,false,false><<<NPIX/64, 256, 0, stream>>>(MLP_ARGS, p1, out1, z2w, poolg);
  finalize_kernel<<<1,128,0,stream>>>(p1, mr1, 64);
  if (pool) mlp_kernel<2,false,true ><<<NPIX/64, 256, 0, stream>>>(MLP_ARGS, p2, out1, z2w, poolg);
  else      mlp_kernel<2,false,false><<<NPIX/64, 256, 0, stream>>>(MLP_ARGS, p2, out1, z2w, poolg);
  finalize_kernel<<<1,128,0,stream>>>(p2, mr2, 64);
  if (pool) mlp_kernel<3,true ,true ><<<NPIX/64, 256, 0, stream>>>(MLP_ARGS, p3, out1, z2w, poolg);
  else      mlp_kernel<3,false,false><<<NPIX/64, 256, 0, stream>>>(MLP_ARGS, p3, out1, z2w, poolg);
  finalize_kernel<<<1,128,0,stream>>>(p3, mr3, 128);
  if (pool) pool_kernel<<<NGRP/2, 256, 0, stream>>>(poolg, mr3, g2, be2, out1);
  else      mlp_kernel<4,false,false><<<NPIX/64, 256, 0, stream>>>(MLP_ARGS, p3, out1, z2w, poolg);
#undef MLP_ARGS
}

// Round 14
// 712.700 us; speedup vs baseline: 1.5007x; 1.1111x over previous
//
#include <hip/hip_runtime.h>
#include <math.h>

#define BB 16
#define NN 4096
#define SS 512
#define KK 32
#define NPIX (BB*SS*KK)          /* 262144 pixels (b,s,k) */
#define NGRP (BB*SS)             /* 8192 groups */

static constexpr float R2F  = (float)0.16000000000000003;  // RADIUS**2 as f32
static constexpr float EPSF = 1e-5f;

// ---------------- workspace layout (bytes) ----------------
constexpr size_t OFF_NXYZ = 0;                     // B*S*3 f32  = 98304
constexpr size_t OFF_GRP  = 98304;                 // B*S*NS i32 = 1048576
constexpr size_t OFF_P1   = 98304 + 1048576;       // 2*64*32 f64  = 32768
constexpr size_t OFF_P2   = OFF_P1 + 32768;
constexpr size_t OFF_P3   = OFF_P2 + 32768;        // 2*128*32 f64 = 65536
constexpr size_t OFF_MR1  = OFF_P3 + 65536;        // 64*2 f32
constexpr size_t OFF_MR2  = OFF_MR1 + 512;
constexpr size_t OFF_MR3  = OFF_MR2 + 512;         // 128*2 f32
constexpr size_t OFF_Z2   = 2*1024*1024;           // z2 (z3 eliminated r13)
constexpr size_t Z2SZ     = (size_t)NPIX*64*4;     // 67108864
constexpr size_t OFF_POOL = OFF_Z2 + Z2SZ;
constexpr size_t POOLSZ   = (size_t)NGRP*256*4;    // 8388608 (max+min per gid,ch)
constexpr size_t NEED_POOL= OFF_POOL + POOLSZ;     // ~77MB (ws measured >=203MB)

// Packed-u64 DPP max step with LITERAL dpp ctrl (builtin requires constant).
#define DPP_U64MAX(key, ctrl) {                                                  \
    unsigned _hi = (unsigned)((key) >> 32), _lo = (unsigned)(key);               \
    unsigned _h2 = (unsigned)__builtin_amdgcn_update_dpp((int)_hi,(int)_hi,(ctrl),0xf,0xf,false); \
    unsigned _l2 = (unsigned)__builtin_amdgcn_update_dpp((int)_lo,(int)_lo,(ctrl),0xf,0xf,false); \
    unsigned long long _o = ((unsigned long long)_h2 << 32) | _l2;               \
    (key) = (_o > (key)) ? _o : (key); }

// Monotone signed-float <-> uint mapping (uint order == float order).
__device__ __forceinline__ unsigned encf(float f){
  unsigned u = __float_as_uint(f);
  return u ^ (0x80000000u | (unsigned)((int)u >> 31));
}
__device__ __forceinline__ float decf(unsigned e){
  return (e & 0x80000000u) ? __uint_as_float(e ^ 0x80000000u) : __uint_as_float(~e);
}

// ======================= FPS (r12-measured 332us, FROZEN) =======================
__global__ __launch_bounds__(512) void fps_kernel(const float* __restrict__ xyz,
        float* __restrict__ out0, float* __restrict__ nxyz, double* __restrict__ pzero){
  const int b = blockIdx.x;
  const float* xb = xyz + (size_t)b*3*NN;
  __shared__ float4 pt4[NN];                       // 64 KB
  __shared__ __align__(16) unsigned long long skey[2][8];
  __shared__ int hist[SS];
  const int t = threadIdx.x;
  const int lane = t & 63, wv = t >> 6;            // wv in [0,8)
  for (int i = b*512 + t; i < 16384; i += 16*512) pzero[i] = 0.0;
  float rx[8], ry[8], rz[8], rd[8];
#pragma unroll
  for (int j=0;j<8;j++){
    int i = t + 512*j;
    float x = xb[i], y = xb[NN+i], z = xb[2*NN+i];
    rx[j]=x; ry[j]=y; rz[j]=z;
    pt4[i] = make_float4(x,y,z,0.0f);
    rd[j]=1e10f;
  }
  __syncthreads();
  int far = 0;
  for (int s=0;s<SS;s++){
    const int buf = s & 1;
    float4 c = pt4[far];
    if (t==0) hist[s] = far;
    float bv = -1.0f; int bi = 0;
#pragma unroll
    for (int j=0;j<8;j++){
      float dx=__fsub_rn(rx[j],c.x), dy=__fsub_rn(ry[j],c.y), dz=__fsub_rn(rz[j],c.z);
      float d2=__fadd_rn(__fadd_rn(__fmul_rn(dx,dx),__fmul_rn(dy,dy)),__fmul_rn(dz,dz));
      float nd=fminf(rd[j],d2);
      rd[j]=nd;
      if (nd>bv){bv=nd;bi=t+512*j;}   // indices ascend with j -> first-max kept
    }
    unsigned long long key = ((unsigned long long)(unsigned)__float_as_int(bv) << 32)
                           | (unsigned)(~(unsigned)bi);
    DPP_U64MAX(key,0x111); DPP_U64MAX(key,0x112); DPP_U64MAX(key,0x114);
    DPP_U64MAX(key,0x118); DPP_U64MAX(key,0x142); DPP_U64MAX(key,0x143);
    if (lane==63) skey[buf][wv] = key;
    __syncthreads();
    unsigned long long k0=skey[buf][0], k1=skey[buf][1], k2=skey[buf][2], k3=skey[buf][3];
    unsigned long long k4=skey[buf][4], k5=skey[buf][5], k6=skey[buf][6], k7=skey[buf][7];
    unsigned long long m01=(k0>k1)?k0:k1, m23=(k2>k3)?k2:k3;
    unsigned long long m45=(k4>k5)?k4:k5, m67=(k6>k7)?k6:k7;
    unsigned long long mA=(m01>m23)?m01:m23, mB=(m45>m67)?m45:m67;
    unsigned long long m =(mA>mB)?mA:mB;
    far = (int)(~(unsigned)(m & 0xFFFFFFFFull));
  }
  __syncthreads();
  {
    int idx = hist[t];
    float4 c = pt4[idx];
    int gid = b*SS + t;
    nxyz[gid*3+0]=c.x; nxyz[gid*3+1]=c.y; nxyz[gid*3+2]=c.z;
    out0[(b*3+0)*SS+t]=c.x; out0[(b*3+1)*SS+t]=c.y; out0[(b*3+2)*SS+t]=c.z;
  }
}

// ======================= ball query (unchanged, passing) =======================
__global__ __launch_bounds__(256) void ball_kernel(const float* __restrict__ xyz,
        const float* __restrict__ nxyz, int* __restrict__ grp){
  const int gw   = (blockIdx.x*256 + threadIdx.x) >> 6;
  const int lane = threadIdx.x & 63;
  if (gw >= NGRP) return;
  const int b = gw / SS;
  const float* xb = xyz + (size_t)b*3*NN;
  const float nx=nxyz[gw*3+0], ny=nxyz[gw*3+1], nz=nxyz[gw*3+2];
  const float sn = __fadd_rn(__fadd_rn(__fmul_rn(nx,nx),__fmul_rn(ny,ny)),__fmul_rn(nz,nz));
  int cnt=0, first=-1;
  int* g = grp + (size_t)gw*KK;
  for (int c=0;c<NN/64 && cnt<KK;c++){
    int i=c*64+lane;
    float x=xb[i], y=xb[NN+i], z=xb[2*NN+i];
    float sxx=__fadd_rn(__fadd_rn(__fmul_rn(x,x),__fmul_rn(y,y)),__fmul_rn(z,z));
    float dot=__fadd_rn(__fadd_rn(__fmul_rn(nx,x),__fmul_rn(ny,y)),__fmul_rn(nz,z));
    float sqr=__fsub_rn(__fadd_rn(sn,sxx),__fmul_rn(2.0f,dot));
    bool m = (sqr <= R2F);
    unsigned long long mask = __ballot(m);
    if (m){
      int pos = cnt + __popcll(mask & ((1ull<<lane)-1ull));
      if (pos < KK) g[pos] = i;
    }
    if (first<0 && mask) first = c*64 + (__ffsll((long long)mask) - 1);
    cnt += __popcll(mask);
  }
  if (cnt < KK && lane >= cnt && lane < KK) g[lane] = first;
}

// ======================= finalize (kept for mr3 + fallback) =======================
__global__ void finalize_kernel(const double* __restrict__ part, float* __restrict__ mr, int C){
  int o = threadIdx.x;
  if (o < C){
    double s1=0.0, s2=0.0;
    for (int k=0;k<32;k++){ s1 += part[o*32+k]; s2 += part[(C+o)*32+k]; }
    const double n = (double)NPIX;
    double mean = s1/n;
    double var  = s2/n - mean*mean;
    mr[2*o]   = (float)mean;
    mr[2*o+1] = (float)(1.0/sqrt(var + (double)EPSF));
  }
}

// ======================= tiled MLP chain =======================
// r14: (1) INFIN — stages 2/3 compute the PREVIOUS layer's mean/rstd in-block
// from the f64 partials (identical f64 expression tree as finalize_kernel ->
// bit-identical mr), removing the two mid-chain 1-block finalize launches.
// (2) stats wave-pre-reduce — lanes {l,l^16,l^32,l^48} share a channel; two
// __shfl_xor collapse them, only lanes<16 hit LDS atomics (4x fewer, 4-way).
constexpr int XIN = 0;          // 6*68   = 408
constexpr int W0F = 408;        // 6*64   = 384
constexpr int B0F = 792;        // 64
constexpr int W1F = 856;        // 64*64  = 4096
constexpr int B1F = 4952;       // 64
constexpr int XBF = 5016;       // 64*68  = 4352
constexpr int SRF = 9368;       // 256  (f32 stats red)
constexpr int MRLs= 9624;       // 128  (in-block mr, small layout)
constexpr int W2F = 9752;       // 64*128 = 8192
constexpr int B2F = 17944;      // 128
constexpr int POOLU = 18072;    // 512 u32: [max 2x128][min 2x128]
constexpr int SM_SMALL = 9752;  // stages 1,2 (+MRL appended below)
constexpr int SM_SMALL_T = 9752;          // stage2 total = MRLs+128
constexpr int SM_BIG_T   = 18072+512;     // stage3/4 total (74.3 KB -> 2 blocks/CU)

template<int STAGE, bool POOL, bool Z2IO, bool INFIN>
__global__ __launch_bounds__(256,2) void mlp_kernel(
    const float* __restrict__ xyz, const float* __restrict__ pts,
    const float* __restrict__ nxyz, const int* __restrict__ grp,
    const float* __restrict__ w0, const float* __restrict__ b0,
    const float* __restrict__ mr1, const float* __restrict__ g0, const float* __restrict__ be0,
    const float* __restrict__ w1, const float* __restrict__ b1,
    const float* __restrict__ mr2, const float* __restrict__ g1, const float* __restrict__ be1,
    const float* __restrict__ w2, const float* __restrict__ b2,
    const float* __restrict__ mr3, const float* __restrict__ g2, const float* __restrict__ be2,
    const double* __restrict__ finp, double* __restrict__ part, float* __restrict__ out1,
    float* __restrict__ z2w, unsigned* __restrict__ poolg)
{
  __shared__ float sm[(STAGE>=3)? SM_BIG_T : (SM_SMALL_T+128)];
  const int t   = threadIdx.x;
  const int blk = blockIdx.x;
  const int tx  = t & 15, ty = t >> 4;
  const int p0  = blk*64;
  const int slot = blk & 31;
  const int lane = t & 63;
  constexpr bool SKIP12 = (STAGE==3 && Z2IO);   // z2 sourced from global
  constexpr int MRL = (STAGE>=3)? (POOLU+512) : MRLs;   // big layout: after POOLU

  sm[SRF + t] = 0.0f;   // stats slot
  if constexpr (STAGE==3 && POOL){
    unsigned* pu = (unsigned*)sm;
    pu[POOLU + t]       = 0u;           // max accumulator
    pu[POOLU + 256 + t] = 0xFFFFFFFFu;  // min accumulator
  }

  // in-block finalize of previous layer's stats (64 channels, f64; identical
  // expression tree to finalize_kernel -> bit-identical mr)
  if constexpr (INFIN){
    if (t < 64){
      double s1=0.0, s2=0.0;
      for (int k=0;k<32;k++){ s1 += finp[t*32+k]; s2 += finp[(64+t)*32+k]; }
      const double n = (double)NPIX;
      double mean = s1/n;
      double var  = s2/n - mean*mean;
      sm[MRL+2*t]   = (float)mean;
      sm[MRL+2*t+1] = (float)(1.0/sqrt(var + (double)EPSF));
    }
  }

  if constexpr (!SKIP12){
    for (int i=t;i<384;i+=256){ int o=i/6, c=i-o*6; sm[W0F + c*64 + o] = w0[i]; }
    if (t<64) sm[B0F+t] = b0[t];
    if constexpr (STAGE>=2){
      for (int i=t;i<4096;i+=256){ int o=i&63, c=i>>6; sm[W1F + c*64 + o] = w1[o*64+c]; }
      if (t<64) sm[B1F+t] = b1[t];
    }
    for (int i=t;i<384;i+=256){
      int c=i>>6, px=i&63, p=p0+px, gid=p>>5, bb=p>>14;
      int idx = grp[p];
      float v;
      if (c<3) v = __fsub_rn(xyz[(size_t)bb*3*NN + c*NN + idx], nxyz[gid*3+c]);
      else     v = pts[(size_t)bb*3*NN + (c-3)*NN + idx];
      sm[XIN + c*68 + px] = v;
    }
  }
  if constexpr (STAGE>=3){
    for (int i=t;i<8192;i+=256){ int o=i&127, c=i>>7; sm[W2F + c*128 + o] = w2[o*64+c]; }
    if (t<128) sm[B2F+t] = b2[t];
  }
  __syncthreads();

  float z[4][4];
  if constexpr (SKIP12){
#pragma unroll
    for (int i=0;i<4;i++){
      float4 v = *(const float4*)&z2w[(size_t)(p0 + ty*4 + i)*64 + tx*4];
      z[i][0]=v.x; z[i][1]=v.y; z[i][2]=v.z; z[i][3]=v.w;
    }
  } else {
    // ---- layer 1: 6 -> 64 ----
#pragma unroll
    for (int i=0;i<4;i++)
#pragma unroll
      for (int j=0;j<4;j++) z[i][j]=0.0f;
#pragma unroll
    for (int k=0;k<6;k++){
      float4 xv = *(const float4*)&sm[XIN + k*68 + ty*4];
      float4 wv = *(const float4*)&sm[W0F + k*64 + tx*4];
      const float xs[4]={xv.x,xv.y,xv.z,xv.w};
      const float wsv[4]={wv.x,wv.y,wv.z,wv.w};
#pragma unroll
      for (int i=0;i<4;i++)
#pragma unroll
        for (int j=0;j<4;j++) z[i][j] = fmaf(xs[i], wsv[j], z[i][j]);
    }
#pragma unroll
    for (int i=0;i<4;i++)
#pragma unroll
      for (int j=0;j<4;j++) z[i][j] = __fadd_rn(z[i][j], sm[B0F + tx*4 + j]);

    if constexpr (STAGE==1){
#pragma unroll
      for (int j=0;j<4;j++){
        float s1=0.0f, s2=0.0f;
#pragma unroll
        for (int i=0;i<4;i++){ s1 = __fadd_rn(s1, z[i][j]); s2 = fmaf(z[i][j], z[i][j], s2); }
        s1 += __shfl_xor(s1,16); s1 += __shfl_xor(s1,32);
        s2 += __shfl_xor(s2,16); s2 += __shfl_xor(s2,32);
        if (lane<16){
          atomicAdd(&sm[SRF + (tx*4+j)*2    ], s1);
          atomicAdd(&sm[SRF + (tx*4+j)*2 + 1], s2);
        }
      }
      __syncthreads();
      if (t<128){ int ch=t>>1, m=t&1;
        atomicAdd(part + (size_t)((m? 64+ch : ch)*32 + slot), (double)sm[SRF+t]);
      }
      return;
    }

    // norm+relu(mr1) -> xbuf
#pragma unroll
    for (int j=0;j<4;j++){
      int ch = tx*4+j;
      float m, r;
      if constexpr (INFIN){ m=sm[MRL+2*ch]; r=sm[MRL+2*ch+1]; }
      else                { m=mr1[2*ch];   r=mr1[2*ch+1];   }
      float gg=g0[ch], bt=be0[ch];
      float4 o;
      o.x = fmaxf(fmaf(__fmul_rn(__fsub_rn(z[0][j],m),r), gg, bt), 0.0f);
      o.y = fmaxf(fmaf(__fmul_rn(__fsub_rn(z[1][j],m),r), gg, bt), 0.0f);
      o.z = fmaxf(fmaf(__fmul_rn(__fsub_rn(z[2][j],m),r), gg, bt), 0.0f);
      o.w = fmaxf(fmaf(__fmul_rn(__fsub_rn(z[3][j],m),r), gg, bt), 0.0f);
      *(float4*)&sm[XBF + ch*68 + ty*4] = o;
    }
    __syncthreads();

    // ---- layer 2: 64 -> 64 ----
#pragma unroll
    for (int i=0;i<4;i++)
#pragma unroll
      for (int j=0;j<4;j++) z[i][j]=0.0f;
#pragma unroll 8
    for (int k=0;k<64;k++){
      float4 xv = *(const float4*)&sm[XBF + k*68 + ty*4];
      float4 wv = *(const float4*)&sm[W1F + k*64 + tx*4];
      const float xs[4]={xv.x,xv.y,xv.z,xv.w};
      const float wsv[4]={wv.x,wv.y,wv.z,wv.w};
#pragma unroll
      for (int i=0;i<4;i++)
#pragma unroll
        for (int j=0;j<4;j++) z[i][j] = fmaf(xs[i], wsv[j], z[i][j]);
    }
#pragma unroll
    for (int i=0;i<4;i++)
#pragma unroll
      for (int j=0;j<4;j++) z[i][j] = __fadd_rn(z[i][j], sm[B1F + tx*4 + j]);

    if constexpr (STAGE==2){
      if constexpr (Z2IO){
#pragma unroll
        for (int i=0;i<4;i++)
          *(float4*)&z2w[(size_t)(p0 + ty*4 + i)*64 + tx*4]
              = make_float4(z[i][0], z[i][1], z[i][2], z[i][3]);
      }
#pragma unroll
      for (int j=0;j<4;j++){
        float s1=0.0f, s2=0.0f;
#pragma unroll
        for (int i=0;i<4;i++){ s1 = __fadd_rn(s1, z[i][j]); s2 = fmaf(z[i][j], z[i][j], s2); }
        s1 += __shfl_xor(s1,16); s1 += __shfl_xor(s1,32);
        s2 += __shfl_xor(s2,16); s2 += __shfl_xor(s2,32);
        if (lane<16){
          atomicAdd(&sm[SRF + (tx*4+j)*2    ], s1);
          atomicAdd(&sm[SRF + (tx*4+j)*2 + 1], s2);
        }
      }
      __syncthreads();
      if (t<128){ int ch=t>>1, m=t&1;
        atomicAdd(part + (size_t)((m? 64+ch : ch)*32 + slot), (double)sm[SRF+t]);
      }
      return;
    }
  }

  if constexpr (STAGE>=3){
    __syncthreads();   // WAR guard on XBF (harmless in SKIP12 path)
#pragma unroll
    for (int j=0;j<4;j++){
      int ch = tx*4+j;
      float m, r;
      if constexpr (INFIN){ m=sm[MRL+2*ch]; r=sm[MRL+2*ch+1]; }
      else                { m=mr2[2*ch];   r=mr2[2*ch+1];   }
      float gg=g1[ch], bt=be1[ch];
      float4 o;
      o.x = fmaxf(fmaf(__fmul_rn(__fsub_rn(z[0][j],m),r), gg, bt), 0.0f);
      o.y = fmaxf(fmaf(__fmul_rn(__fsub_rn(z[1][j],m),r), gg, bt), 0.0f);
      o.z = fmaxf(fmaf(__fmul_rn(__fsub_rn(z[2][j],m),r), gg, bt), 0.0f);
      o.w = fmaxf(fmaf(__fmul_rn(__fsub_rn(z[3][j],m),r), gg, bt), 0.0f);
      *(float4*)&sm[XBF + ch*68 + ty*4] = o;
    }
    __syncthreads();

    // ---- layer 3: 64 -> 128 ----
    float a3[4][8];
#pragma unroll
    for (int i=0;i<4;i++)
#pragma unroll
      for (int j=0;j<8;j++) a3[i][j]=0.0f;
#pragma unroll 4
    for (int k=0;k<64;k++){
      float4 xv  = *(const float4*)&sm[XBF + k*68  + ty*4];
      float4 wv0 = *(const float4*)&sm[W2F + k*128 + tx*4];
      float4 wv1 = *(const float4*)&sm[W2F + k*128 + 64 + tx*4];
      const float xs[4]={xv.x,xv.y,xv.z,xv.w};
      const float wsv[8]={wv0.x,wv0.y,wv0.z,wv0.w, wv1.x,wv1.y,wv1.z,wv1.w};
#pragma unroll
      for (int i=0;i<4;i++)
#pragma unroll
        for (int j=0;j<8;j++) a3[i][j] = fmaf(xs[i], wsv[j], a3[i][j]);
    }
#pragma unroll
    for (int i=0;i<4;i++)
#pragma unroll
      for (int j=0;j<8;j++){
        int ch = (j<4)? (tx*4+j) : (64+tx*4+(j-4));
        a3[i][j] = __fadd_rn(a3[i][j], sm[B2F + ch]);
      }

    if constexpr (STAGE==3){
      if constexpr (POOL){
        unsigned* pu = (unsigned*)sm;
        const int gl = ty>>3;
#pragma unroll
        for (int j=0;j<8;j++){
          int ch = (j<4)? (tx*4+j) : (64+tx*4+(j-4));
          float mx = fmaxf(fmaxf(a3[0][j],a3[1][j]), fmaxf(a3[2][j],a3[3][j]));
          float mn = fminf(fminf(a3[0][j],a3[1][j]), fminf(a3[2][j],a3[3][j]));
          atomicMax(&pu[POOLU + gl*128 + ch], encf(mx));
          atomicMin(&pu[POOLU + 256 + gl*128 + ch], encf(mn));
        }
      }
#pragma unroll
      for (int j=0;j<8;j++){
        int ch = (j<4)? (tx*4+j) : (64+tx*4+(j-4));
        float s1=0.0f, s2=0.0f;
#pragma unroll
        for (int i=0;i<4;i++){ s1 = __fadd_rn(s1, a3[i][j]); s2 = fmaf(a3[i][j], a3[i][j], s2); }
        s1 += __shfl_xor(s1,16); s1 += __shfl_xor(s1,32);
        s2 += __shfl_xor(s2,16); s2 += __shfl_xor(s2,32);
        if (lane<16){
          atomicAdd(&sm[SRF + ch*2    ], s1);
          atomicAdd(&sm[SRF + ch*2 + 1], s2);
        }
      }
      __syncthreads();
      { int ch=t>>1, m=t&1;
        atomicAdd(part + (size_t)((m? 128+ch : ch)*32 + slot), (double)sm[SRF+t]);
      }
      if constexpr (POOL){
        unsigned* pu = (unsigned*)sm;
        const int gl2 = t>>7, ch2 = t&127;
        size_t base = (size_t)(blk*2+gl2)*256;
        poolg[base + ch2]       = pu[POOLU + gl2*128 + ch2];
        poolg[base + 128 + ch2] = pu[POOLU + 256 + gl2*128 + ch2];
      }
      return;
    }

    if constexpr (STAGE==4){
      const int grp_l = ty>>3;
      unsigned* omax = (unsigned*)sm;
#pragma unroll
      for (int j=0;j<8;j++){
        int ch = (j<4)? (tx*4+j) : (64+tx*4+(j-4));
        float m=mr3[2*ch], r=mr3[2*ch+1], gg=g2[ch], bt=be2[ch];
        float vmax=0.0f;
#pragma unroll
        for (int i=0;i<4;i++){
          float v = fmaxf(fmaf(__fmul_rn(__fsub_rn(a3[i][j],m),r), gg, bt), 0.0f);
          vmax = fmaxf(vmax, v);
        }
        atomicMax(&omax[SRF + grp_l*128 + ch], __float_as_uint(vmax));
      }
      __syncthreads();
      { int g = t>>7, o = t&127;
        int gid = blk*2 + g, bb = gid>>9, s = gid&511;
        out1[((size_t)(bb*128+o))*512 + s] = __uint_as_float(omax[SRF + t]);
      }
    }
  }
}

// ======================= pooled-minmax finalizer =======================
__global__ __launch_bounds__(256) void pool_kernel(const unsigned* __restrict__ poolg,
        const float* __restrict__ mr3, const float* __restrict__ g2,
        const float* __restrict__ be2, float* __restrict__ out1){
  const int t = threadIdx.x;
  const int gl = t>>7, ch = t&127;
  const int gid = blockIdx.x*2 + gl;            // b*SS+s
  const int bb = gid>>9, s = gid&511;
  float fmx = decf(poolg[(size_t)gid*256 + ch]);
  float fmn = decf(poolg[(size_t)gid*256 + 128 + ch]);
  float m=mr3[2*ch], r=mr3[2*ch+1], gg=g2[ch], bt=be2[ch];
  float ya = fmaxf(fmaf(__fmul_rn(__fsub_rn(fmx,m),r), gg, bt), 0.0f);
  float yb = fmaxf(fmaf(__fmul_rn(__fsub_rn(fmn,m),r), gg, bt), 0.0f);
  out1[((size_t)(bb*128+ch))*SS + s] = fmaxf(ya, yb);
}

// ======================= launch =======================
extern "C" void kernel_launch(void* const* d_in, const int* in_sizes, int n_in,
                              void* d_out, int out_size, void* d_ws, size_t ws_size,
                              hipStream_t stream){
  const float* xyz = (const float*)d_in[0];
  const float* pts = (const float*)d_in[1];
  const float* w0  = (const float*)d_in[2];  const float* b0  = (const float*)d_in[3];
  const float* g0  = (const float*)d_in[4];  const float* be0 = (const float*)d_in[5];
  const float* w1  = (const float*)d_in[6];  const float* b1  = (const float*)d_in[7];
  const float* g1  = (const float*)d_in[8];  const float* be1 = (const float*)d_in[9];
  const float* w2  = (const float*)d_in[10]; const float* b2  = (const float*)d_in[11];
  const float* g2  = (const float*)d_in[12]; const float* be2 = (const float*)d_in[13];

  float* out  = (float*)d_out;
  float* out1 = out + BB*3*SS;
  char*  ws   = (char*)d_ws;

  float*    nxyz  = (float*)(ws + OFF_NXYZ);
  int*      grp   = (int*)  (ws + OFF_GRP);
  double*   p1    = (double*)(ws + OFF_P1);
  double*   p2    = (double*)(ws + OFF_P2);
  double*   p3    = (double*)(ws + OFF_P3);
  float*    mr1   = (float*)(ws + OFF_MR1);
  float*    mr2   = (float*)(ws + OFF_MR2);
  float*    mr3   = (float*)(ws + OFF_MR3);
  float*    z2w   = (float*)(ws + OFF_Z2);
  unsigned* poolg = (unsigned*)(ws + OFF_POOL);

  const bool pool = (ws_size >= NEED_POOL);   // ~77MB; measured ws >= 203MB

  fps_kernel <<<BB, 512, 0, stream>>>(xyz, out, nxyz, p1);
  ball_kernel<<<NGRP*64/256, 256, 0, stream>>>(xyz, nxyz, grp);

#define MLP_ARGS xyz, pts, nxyz, grp, w0, b0, mr1, g0, be0, w1, b1, mr2, g1, be1, w2, b2, mr3, g2, be2
  if (pool){
    mlp_kernel<1,false,false,false><<<NPIX/64, 256, 0, stream>>>(MLP_ARGS, p1, p1, out1, z2w, poolg);
    mlp_kernel<2,false,true ,true ><<<NPIX/64, 256, 0, stream>>>(MLP_ARGS, p1, p2, out1, z2w, poolg);
    mlp_kernel<3,true ,true ,true ><<<NPIX/64, 256, 0, stream>>>(MLP_ARGS, p2, p3, out1, z2w, poolg);
    finalize_kernel<<<1,128,0,stream>>>(p3, mr3, 128);
    pool_kernel<<<NGRP/2, 256, 0, stream>>>(poolg, mr3, g2, be2, out1);
  } else {
    mlp_kernel<1,false,false,false><<<NPIX/64, 256, 0, stream>>>(MLP_ARGS, p1, p1, out1, z2w, poolg);
    finalize_kernel<<<1,128,0,stream>>>(p1, mr1, 64);
    mlp_kernel<2,false,false,false><<<NPIX/64, 256, 0, stream>>>(MLP_ARGS, p1, p2, out1, z2w, poolg);
    finalize_kernel<<<1,128,0,stream>>>(p2, mr2, 64);
    mlp_kernel<3,false,false,false><<<NPIX/64, 256, 0, stream>>>(MLP_ARGS, p2, p3, out1, z2w, poolg);
    finalize_kernel<<<1,128,0,stream>>>(p3, mr3, 128);
    mlp_kernel<4,false,false,false><<<NPIX/64, 256, 0, stream>>>(MLP_ARGS, p3, p3, out1, z2w, poolg);
  }
#undef MLP_ARGS
}